// Round 4
// baseline (959.952 us; speedup 1.0000x reference)
//
#include <hip/hip_runtime.h>
#include <hip/hip_bf16.h>

typedef __attribute__((ext_vector_type(8))) short short8;
typedef __attribute__((ext_vector_type(4))) float f32x4;
typedef __attribute__((ext_vector_type(8))) unsigned short u16x8;
typedef __attribute__((ext_vector_type(4))) unsigned short u16x4;

// ---------- helpers ----------
__device__ __forceinline__ unsigned short f2bf(float f) {
  unsigned u = __float_as_uint(f);
  u += 0x7fffu + ((u >> 16) & 1u);          // round-to-nearest-even
  return (unsigned short)(u >> 16);
}
__device__ __forceinline__ float silu_f(float x) { return x / (1.f + __expf(-x)); }
__device__ __forceinline__ float red16(float v) {  // sum across 16-lane group (shfl)
  v += __shfl_xor(v, 1); v += __shfl_xor(v, 2);
  v += __shfl_xor(v, 4); v += __shfl_xor(v, 8);
  return v;
}
// DPP 16-lane sum: quad xor1, quad xor2, half-mirror, row-mirror
template <int CTRL>
__device__ __forceinline__ float dpp_mv(float v) {
  return __int_as_float(__builtin_amdgcn_update_dpp(0, __float_as_int(v), CTRL, 0xF, 0xF, true));
}
__device__ __forceinline__ float red16d(float v) {
  v += dpp_mv<0xB1>(v);   // quad_perm [1,0,3,2]
  v += dpp_mv<0x4E>(v);   // quad_perm [2,3,0,1]
  v += dpp_mv<0x141>(v);  // row_half_mirror
  v += dpp_mv<0x140>(v);  // row_mirror
  return v;
}
__device__ __forceinline__ void gload16(const void* g, void* l) {
  __builtin_amdgcn_global_load_lds((const __attribute__((address_space(1))) void*)g,
                                   (__attribute__((address_space(3))) void*)l, 16, 0, 0);
}

// ---------- transpose fp32 [R][C] -> bf16 [C][R] ----------
__global__ void __launch_bounds__(256) trans_kernel(const float* __restrict__ src,
                                                    unsigned short* __restrict__ dst,
                                                    int R, int C) {
  __shared__ float tile[32][33];
  const int tx = threadIdx.x & 31, ty = threadIdx.x >> 5;
  const int c = blockIdx.x * 32 + tx;
#pragma unroll
  for (int i = 0; i < 32; i += 8) {
    int r = blockIdx.y * 32 + ty + i;
    if (r < R && c < C) tile[ty + i][tx] = src[(size_t)r * C + c];
  }
  __syncthreads();
  const int rc = blockIdx.y * 32 + tx;
#pragma unroll
  for (int i = 0; i < 32; i += 8) {
    int cc = blockIdx.x * 32 + ty + i;
    if (cc < C && rc < R) dst[(size_t)cc * R + rc] = f2bf(tile[tx][ty + i]);
  }
}

// ---------- rmsnorm (D=2048) -> bf16 ----------
__global__ void __launch_bounds__(256) rmsnorm_bf16_kernel(const float* __restrict__ x,
                                                           const float* __restrict__ w,
                                                           unsigned short* __restrict__ outb) {
  const int t = blockIdx.x, tid = threadIdx.x;
  const float* xr = x + (size_t)t * 2048 + tid * 8;
  float4 v0 = *(const float4*)xr, v1 = *(const float4*)(xr + 4);
  float ss = v0.x*v0.x + v0.y*v0.y + v0.z*v0.z + v0.w*v0.w
           + v1.x*v1.x + v1.y*v1.y + v1.z*v1.z + v1.w*v1.w;
#pragma unroll
  for (int m = 1; m < 64; m <<= 1) ss += __shfl_xor(ss, m);
  __shared__ float sb[4];
  if ((tid & 63) == 0) sb[tid >> 6] = ss;
  __syncthreads();
  float rn = rsqrtf((sb[0] + sb[1] + sb[2] + sb[3]) * (1.f / 2048.f) + 1e-6f);
  const float* wr = w + tid * 8;
  float4 w0 = *(const float4*)wr, w1 = *(const float4*)(wr + 4);
  u16x8 r;
  r[0]=f2bf(v0.x*rn*w0.x); r[1]=f2bf(v0.y*rn*w0.y); r[2]=f2bf(v0.z*rn*w0.z); r[3]=f2bf(v0.w*rn*w0.w);
  r[4]=f2bf(v1.x*rn*w1.x); r[5]=f2bf(v1.y*rn*w1.y); r[6]=f2bf(v1.z*rn*w1.z); r[7]=f2bf(v1.w*rn*w1.w);
  *(u16x8*)(outb + (size_t)t * 2048 + tid * 8) = r;
}

// ---------- x1 = x + y ; h2b = bf16(rmsnorm(x1)*w) ----------
__global__ void __launch_bounds__(256) add_rmsnorm_kernel(const float* __restrict__ x,
                                                          const float* __restrict__ y,
                                                          const float* __restrict__ w,
                                                          float* __restrict__ x1,
                                                          unsigned short* __restrict__ h2b) {
  const int t = blockIdx.x, tid = threadIdx.x;
  const int c = tid * 8;
  const float* xr = x + (size_t)t * 2048 + c;
  const float* yr = y + (size_t)t * 2048 + c;
  float s[8]; float ss = 0.f;
  float4 a0 = *(const float4*)xr, a1 = *(const float4*)(xr + 4);
  float4 b0 = *(const float4*)yr, b1 = *(const float4*)(yr + 4);
  s[0]=a0.x+b0.x; s[1]=a0.y+b0.y; s[2]=a0.z+b0.z; s[3]=a0.w+b0.w;
  s[4]=a1.x+b1.x; s[5]=a1.y+b1.y; s[6]=a1.z+b1.z; s[7]=a1.w+b1.w;
#pragma unroll
  for (int j = 0; j < 8; j++) ss += s[j] * s[j];
#pragma unroll
  for (int m = 1; m < 64; m <<= 1) ss += __shfl_xor(ss, m);
  __shared__ float sb[4];
  if ((tid & 63) == 0) sb[tid >> 6] = ss;
  __syncthreads();
  float rn = rsqrtf((sb[0] + sb[1] + sb[2] + sb[3]) * (1.f / 2048.f) + 1e-6f);
  float* xo = x1 + (size_t)t * 2048 + c;
  *(float4*)xo = *(float4*)&s[0];
  *(float4*)(xo + 4) = *(float4*)&s[4];
  const float* wr = w + c;
  float4 w0 = *(const float4*)wr, w1 = *(const float4*)(wr + 4);
  float wv[8] = {w0.x,w0.y,w0.z,w0.w,w1.x,w1.y,w1.z,w1.w};
  u16x8 r;
#pragma unroll
  for (int j = 0; j < 8; j++) r[j] = f2bf(s[j] * rn * wv[j]);
  *(u16x8*)(h2b + (size_t)t * 2048 + c) = r;
}

// ---------- bf16 GEMM: C[M,N] = A[M,K] * Bt[N,K]^T  (m97-style, strided) ----------
__global__ void __launch_bounds__(256) gemm_bt_kernel(const unsigned short* __restrict__ A,
                                                      const unsigned short* __restrict__ Bt,
                                                      float* __restrict__ C,
                                                      int M, int N, int K, int lda, int ldb) {
  __shared__ unsigned short As[128][32];
  __shared__ unsigned short Bs[128][32];
  const int tid = threadIdx.x;
  const int m0 = blockIdx.x << 7, n0 = blockIdx.y << 7;
  const int wave = tid >> 6, lane = tid & 63;
  const int wm = (wave >> 1) << 6, wn = (wave & 1) << 6;
  const int lrow = lane >> 2, lcol = lane & 3;
  const int ar0 = wave * 16 + lrow;
  const int ar1 = ar0 + 64;
  int br0 = n0 + ar0; br0 = br0 < N ? br0 : N - 1;
  int br1 = n0 + ar1; br1 = br1 < N ? br1 : N - 1;
  const unsigned short* Aptr0 = A + (size_t)(m0 + ar0) * lda + ((lcol ^ (ar0 & 3)) << 3);
  const unsigned short* Aptr1 = A + (size_t)(m0 + ar1) * lda + ((lcol ^ (ar1 & 3)) << 3);
  const unsigned short* Bptr0 = Bt + (size_t)br0 * ldb + ((lcol ^ (ar0 & 3)) << 3);
  const unsigned short* Bptr1 = Bt + (size_t)br1 * ldb + ((lcol ^ (ar1 & 3)) << 3);
  unsigned short* lA0 = &As[wave * 16][0];
  unsigned short* lA1 = &As[64 + wave * 16][0];
  unsigned short* lB0 = &Bs[wave * 16][0];
  unsigned short* lB1 = &Bs[64 + wave * 16][0];
  const int frow = lane & 15, fkb = lane >> 4;
  f32x4 acc[4][4];
#pragma unroll
  for (int i = 0; i < 4; i++)
#pragma unroll
    for (int j = 0; j < 4; j++) acc[i][j] = (f32x4){0.f, 0.f, 0.f, 0.f};

  for (int k0 = 0; k0 < K; k0 += 32) {
    gload16(Aptr0 + k0, lA0);
    gload16(Aptr1 + k0, lA1);
    gload16(Bptr0 + k0, lB0);
    gload16(Bptr1 + k0, lB1);
    __syncthreads();
    short8 af[4], bfr[4];
#pragma unroll
    for (int i = 0; i < 4; i++) {
      int ra = wm + i * 16 + frow;
      af[i] = *(const short8*)&As[ra][(fkb ^ (ra & 3)) << 3];
      int rb = wn + i * 16 + frow;
      bfr[i] = *(const short8*)&Bs[rb][(fkb ^ (rb & 3)) << 3];
    }
#pragma unroll
    for (int i = 0; i < 4; i++)
#pragma unroll
      for (int j = 0; j < 4; j++)
        acc[i][j] = __builtin_amdgcn_mfma_f32_16x16x32_bf16(af[i], bfr[j], acc[i][j], 0, 0, 0);
    __syncthreads();
  }
  const int crow = (lane >> 4) << 2, ccol = lane & 15;
#pragma unroll
  for (int i = 0; i < 4; i++) {
    const int gr = m0 + wm + i * 16 + crow;
#pragma unroll
    for (int j = 0; j < 4; j++) {
      const int gc = n0 + wn + j * 16 + ccol;
      if (gc < N) {
#pragma unroll
        for (int r = 0; r < 4; r++) C[(size_t)(gr + r) * N + gc] = acc[i][j][r];
      }
    }
  }
}

// ---------- causal dwconv(K=4) + silu + per-head l2norm + qk dot ----------
__global__ void __launch_bounds__(256) conv_kernel(const float* __restrict__ proj,
                                                   const float* __restrict__ cq,
                                                   const float* __restrict__ ck,
                                                   const float* __restrict__ cv,
                                                   float* __restrict__ q, float* __restrict__ k,
                                                   float* __restrict__ v,
                                                   float* __restrict__ qkbuf) {
  const int t = blockIdx.x, tid = threadIdx.x;
  const int c = tid << 3;
  float aq[8] = {0,0,0,0,0,0,0,0}, ak[8] = {0,0,0,0,0,0,0,0}, av[8] = {0,0,0,0,0,0,0,0};
#pragma unroll
  for (int i = 0; i < 4; i++) {
    const int tt = t + i - 3;
    if (tt < 0) continue;
    const float* pr = proj + (size_t)tt * 6144;
    float pq[8], pk[8], pv[8], w0[8], w1[8], w2[8];
    *(float4*)&pq[0] = *(const float4*)(pr + c);        *(float4*)&pq[4] = *(const float4*)(pr + c + 4);
    *(float4*)&pk[0] = *(const float4*)(pr + 2048 + c); *(float4*)&pk[4] = *(const float4*)(pr + 2048 + c + 4);
    *(float4*)&pv[0] = *(const float4*)(pr + 4096 + c); *(float4*)&pv[4] = *(const float4*)(pr + 4096 + c + 4);
    *(float4*)&w0[0] = *(const float4*)(cq + i * 2048 + c); *(float4*)&w0[4] = *(const float4*)(cq + i * 2048 + c + 4);
    *(float4*)&w1[0] = *(const float4*)(ck + i * 2048 + c); *(float4*)&w1[4] = *(const float4*)(ck + i * 2048 + c + 4);
    *(float4*)&w2[0] = *(const float4*)(cv + i * 2048 + c); *(float4*)&w2[4] = *(const float4*)(cv + i * 2048 + c + 4);
#pragma unroll
    for (int j = 0; j < 8; j++) { aq[j] += w0[j]*pq[j]; ak[j] += w1[j]*pk[j]; av[j] += w2[j]*pv[j]; }
  }
  float sq[8], sk[8], sv[8]; float ssq = 0.f, ssk = 0.f;
#pragma unroll
  for (int j = 0; j < 8; j++) {
    sq[j] = silu_f(aq[j]); ssq += sq[j]*sq[j];
    sk[j] = silu_f(ak[j]); ssk += sk[j]*sk[j];
    sv[j] = silu_f(av[j]);
  }
  ssq = red16(ssq); ssk = red16(ssk);   // 16 lanes cover one head (128 ch)
  const float rq = rsqrtf(ssq + 1e-6f) * 0.08838834764831845f;  // * DK^-0.5
  const float rk = rsqrtf(ssk + 1e-6f);
  float oq[8], ok[8]; float qkl = 0.f;
#pragma unroll
  for (int j = 0; j < 8; j++) { oq[j] = sq[j]*rq; ok[j] = sk[j]*rk; qkl += oq[j]*ok[j]; }
  qkl = red16(qkl);
  if ((tid & 15) == 0) qkbuf[(size_t)t * 16 + (tid >> 4)] = qkl;
  float* qo = q + (size_t)t * 2048 + c;
  *(float4*)qo = *(float4*)&oq[0]; *(float4*)(qo + 4) = *(float4*)&oq[4];
  float* ko = k + (size_t)t * 2048 + c;
  *(float4*)ko = *(float4*)&ok[0]; *(float4*)(ko + 4) = *(float4*)&ok[4];
  float* vo = v + (size_t)t * 2048 + c;
  *(float4*)vo = *(float4*)&sv[0]; *(float4*)(vo + 4) = *(float4*)&sv[4];
}

// ---------- packed gates: g4[t][h] = (eg, beta, qk, 0); gab->bf16 ----------
__global__ void __launch_bounds__(64) gates_kernel(const float* __restrict__ small,
                                                   const float* __restrict__ wfb,
                                                   const float* __restrict__ a_log,
                                                   const float* __restrict__ dtb,
                                                   const float* __restrict__ qkbuf,
                                                   float4* __restrict__ g4,
                                                   unsigned short* __restrict__ gab) {
  const int t = blockIdx.x, tid = threadIdx.x;
  const float* srow = small + (size_t)t * 272;
  if (tid < 16) {
    float d = dtb[tid];
    for (int j = 0; j < 128; j++) d += srow[j] * wfb[j * 16 + tid];
    float sp = (d > 20.f) ? d : log1pf(expf(d));
    float eg = expf(-expf(a_log[tid]) * sp);
    float b = srow[128 + tid];
    float bt = 1.f / (1.f + expf(-b));
    g4[t * 16 + tid] = make_float4(eg, bt, qkbuf[t * 16 + tid], 0.f);
  }
  for (int j = tid; j < 128; j += 64) gab[(size_t)t * 128 + j] = f2bf(srow[144 + j]);
}

// ---------- gated delta-rule scan (LDS-staged, counted-vmcnt pipeline) ----------
// one wave = 4 v-columns of one head. Chunk = 8 steps staged into LDS via
// global_load_lds (9 loads/chunk: 8x [k row | q row], 1x aux [v cols | g4]).
// Triple-buffered; 1 wave/block -> no barriers, just counted s_waitcnt vmcnt.
__device__ __forceinline__ void stage_chunk(const float* kb, const float* qb,
                                            const float* vb, const float* g4f,
                                            int tbase, float* bkq, float* baux, int lane) {
  const int l32 = lane & 31;
  const float* g = (lane < 32 ? kb : qb) + l32 * 4;
#pragma unroll
  for (int i = 0; i < 8; i++) {
    int t = (tbase + i) & 1023;
    gload16(g + (size_t)t * 2048, bkq + i * 256);
  }
  const int li = lane & 7;
  const int t2 = (tbase + li) & 1023;
  const float* ga;
  if (lane < 8)       ga = vb + (size_t)t2 * 2048;   // 16B = the wave's 4 v-cols
  else if (lane < 16) ga = g4f + (size_t)t2 * 64;    // 16B = g4[t][h]
  else                ga = g4f;                       // junk lanes, valid addr
  gload16(ga, baux);
}

__device__ __forceinline__ void compute_chunk(const float* bkq, const float* baux,
                                              int tbase, float (&S)[8], float* ob,
                                              bool dostore, int kl, int vl) {
#pragma unroll
  for (int i = 0; i < 8; i++) {
    const float* kp = bkq + i * 256 + kl * 8;
    float4 k0 = *(const float4*)kp,         k1 = *(const float4*)(kp + 4);
    float4 q0 = *(const float4*)(kp + 128), q1 = *(const float4*)(kp + 132);
    float  vv = baux[i * 4 + vl];
    float4 g  = *(const float4*)(baux + 32 + i * 4);
    const float eg = g.x, bt = g.y, qk = g.z;
    float a0 = fmaf(k1.x, S[4], k0.x * S[0]);
    float a1 = fmaf(k1.y, S[5], k0.y * S[1]);
    float a2 = fmaf(k1.z, S[6], k0.z * S[2]);
    float a3 = fmaf(k1.w, S[7], k0.w * S[3]);
    float b0 = fmaf(q1.x, S[4], q0.x * S[0]);
    float b1 = fmaf(q1.y, S[5], q0.y * S[1]);
    float b2 = fmaf(q1.z, S[6], q0.z * S[2]);
    float b3 = fmaf(q1.w, S[7], q0.w * S[3]);
    float kS = red16d((a0 + a1) + (a2 + a3));
    float qS = red16d((b0 + b1) + (b2 + b3));
    float delta = fmaf(-(bt * eg), kS, bt * vv);   // bt*(v - eg*kS)
    S[0] = fmaf(k0.x, delta, eg * S[0]);
    S[1] = fmaf(k0.y, delta, eg * S[1]);
    S[2] = fmaf(k0.z, delta, eg * S[2]);
    S[3] = fmaf(k0.w, delta, eg * S[3]);
    S[4] = fmaf(k1.x, delta, eg * S[4]);
    S[5] = fmaf(k1.y, delta, eg * S[5]);
    S[6] = fmaf(k1.z, delta, eg * S[6]);
    S[7] = fmaf(k1.w, delta, eg * S[7]);
    if (dostore) ob[(size_t)(tbase + i) * 2048] = fmaf(qk, delta, eg * qS);
  }
}

__global__ void __launch_bounds__(64, 1) scan_kernel(const float* __restrict__ q,
                                                     const float* __restrict__ k,
                                                     const float* __restrict__ v,
                                                     const float4* __restrict__ g4,
                                                     float* __restrict__ o) {
  __shared__ float lkq[3][2048];    // 3 x 8 steps x (128 k + 128 q)
  __shared__ float laux[3][256];    // 3 x (8x4 v | 8x4 g4 | pad)
  // XCD swizzle: b&7 = XCD -> heads 2x,2x+1 stay on one XCD
  const int b = blockIdx.x;            // 512 = 16 heads * 32 slices
  const int xcd = b & 7, r = b >> 3;
  const int h = (xcd << 1) | (r >> 5);
  const int vbase = (r & 31) << 2;
  const int lane = threadIdx.x;
  const int kl = lane & 15, vl = lane >> 4;
  const float* kb  = k + h * 128;
  const float* qb  = q + h * 128;
  const float* vb  = v + h * 128 + vbase;
  const float* g4f = (const float*)g4 + h * 4;
  float* ob = o + h * 128 + vbase + vl;
  const bool dostore = (kl == 0);
  float* b0 = &lkq[0][0]; float* b1 = &lkq[1][0]; float* b2 = &lkq[2][0];
  float* x0 = &laux[0][0]; float* x1 = &laux[1][0]; float* x2 = &laux[2][0];
  stage_chunk(kb, qb, vb, g4f, 0, b0, x0, lane);
  stage_chunk(kb, qb, vb, g4f, 8, b1, x1, lane);
  asm volatile("s_waitcnt vmcnt(9)" ::: "memory");   // chunk0 resident
  __builtin_amdgcn_sched_barrier(0);
  float S[8] = {0, 0, 0, 0, 0, 0, 0, 0};
  for (int c = 0; c < 128; c++) {
    stage_chunk(kb, qb, vb, g4f, (c + 2) * 8, b2, x2, lane);   // prefetch depth 2
    compute_chunk(b0, x0, c * 8, S, ob, dostore, kl, vl);
    // youngest 17 ops = 9 prefetch loads + 8 o-stores -> chunk c+1 loads retired
    asm volatile("s_waitcnt vmcnt(17)" ::: "memory");
    __builtin_amdgcn_sched_barrier(0);
    float* tb = b0; b0 = b1; b1 = b2; b2 = tb;
    float* tx = x0; x0 = x1; x1 = x2; x2 = tx;
  }
}

// ---------- o_gated = bf16(rmsnorm_head(o)*w * silu(gate)) ----------
__global__ void __launch_bounds__(256) gate_o_kernel(const float* __restrict__ o,
                                                     const float* __restrict__ gate,
                                                     const float* __restrict__ onw,
                                                     unsigned short* __restrict__ ogb) {
  const int t = blockIdx.x, tid = threadIdx.x;
  const int c = tid << 3;
  const float* orow = o + (size_t)t * 2048 + c;
  float ov[8]; *(float4*)&ov[0] = *(const float4*)orow; *(float4*)&ov[4] = *(const float4*)(orow + 4);
  float ss = 0.f;
#pragma unroll
  for (int j = 0; j < 8; j++) ss += ov[j] * ov[j];
  ss = red16(ss);
  const float rn = rsqrtf(ss * (1.f / 128.f) + 1e-6f);
  const int dv = (tid & 15) << 3;
  float wv[8]; *(float4*)&wv[0] = *(const float4*)(onw + dv); *(float4*)&wv[4] = *(const float4*)(onw + dv + 4);
  const float* grow = gate + (size_t)t * 2048 + c;
  float gv[8]; *(float4*)&gv[0] = *(const float4*)grow; *(float4*)&gv[4] = *(const float4*)(grow + 4);
  u16x8 r;
#pragma unroll
  for (int j = 0; j < 8; j++) r[j] = f2bf(ov[j] * rn * wv[j] * silu_f(gv[j]));
  *(u16x8*)(ogb + (size_t)t * 2048 + c) = r;
}

// ---------- swiglu ----------
__global__ void swiglu_kernel(const float* __restrict__ m1, unsigned short* __restrict__ mid) {
  const int NU = 1024 * 2048;
  for (int u = blockIdx.x * blockDim.x + threadIdx.x; u < NU; u += gridDim.x * blockDim.x) {
    const int t = u >> 11;
    const int j4 = (u & 2047) << 2;
    const float* base = m1 + (size_t)t * 16384;
    float4 gv = *(const float4*)(base + j4);
    float4 uv = *(const float4*)(base + 8192 + j4);
    u16x4 r;
    r[0] = f2bf(silu_f(gv.x) * uv.x);
    r[1] = f2bf(silu_f(gv.y) * uv.y);
    r[2] = f2bf(silu_f(gv.z) * uv.z);
    r[3] = f2bf(silu_f(gv.w) * uv.w);
    *(u16x4*)(mid + (size_t)t * 8192 + j4) = r;
  }
}

// ---------- out = a + b + c (split-K down-proj) ----------
__global__ void final_add3_kernel(const float* __restrict__ a, const float* __restrict__ b,
                                  const float* __restrict__ c, float* __restrict__ out) {
  const int NU = 1024 * 512;
  for (int u = blockIdx.x * blockDim.x + threadIdx.x; u < NU; u += gridDim.x * blockDim.x) {
    float4 va = ((const float4*)a)[u];
    float4 vb = ((const float4*)b)[u];
    float4 vc = ((const float4*)c)[u];
    va.x += vb.x + vc.x; va.y += vb.y + vc.y; va.z += vb.z + vc.z; va.w += vb.w + vc.w;
    ((float4*)out)[u] = va;
  }
}

// ---------- ws layout (bytes) ----------
constexpr size_t SZ_WQKVT   = (size_t)6144 * 2048 * 2;
constexpr size_t SZ_WSMALLT = (size_t)272 * 2048 * 2;
constexpr size_t SZ_WGBT    = (size_t)2048 * 128 * 2;
constexpr size_t SZ_WOT     = (size_t)2048 * 2048 * 2;
constexpr size_t SZ_WMLP1T  = (size_t)16384 * 2048 * 2;
constexpr size_t SZ_WDOWNT  = (size_t)2048 * 8192 * 2;
constexpr size_t OFF_WQKVT   = 0;
constexpr size_t OFF_WSMALLT = OFF_WQKVT + SZ_WQKVT;
constexpr size_t OFF_WGBT    = OFF_WSMALLT + SZ_WSMALLT;
constexpr size_t OFF_WOT     = OFF_WGBT + SZ_WGBT;
constexpr size_t OFF_WMLP1T  = OFF_WOT + SZ_WOT;
constexpr size_t OFF_WDOWNT  = OFF_WMLP1T + SZ_WMLP1T;
constexpr size_t A0          = OFF_WDOWNT + SZ_WDOWNT;
constexpr size_t OFF_HB    = A0;
constexpr size_t OFF_PROJ  = OFF_HB + (size_t)1024 * 2048 * 2;
constexpr size_t OFF_SMALL = OFF_PROJ + (size_t)1024 * 6144 * 4;
constexpr size_t OFF_Q     = OFF_SMALL + (size_t)1024 * 272 * 4;
constexpr size_t OFF_K     = OFF_Q + (size_t)1024 * 2048 * 4;
constexpr size_t OFF_V     = OFF_K + (size_t)1024 * 2048 * 4;
constexpr size_t OFF_G     = OFF_V + (size_t)1024 * 2048 * 4;
constexpr size_t OFF_BETA  = OFF_G + (size_t)1024 * 16 * 4;
constexpr size_t OFF_GAB   = OFF_BETA + (size_t)1024 * 16 * 4;
constexpr size_t OFF_GATE  = OFF_GAB + (size_t)1024 * 128 * 2;
constexpr size_t OFF_O     = OFF_GATE + (size_t)1024 * 2048 * 4;
constexpr size_t OFF_OGB   = OFF_O + (size_t)1024 * 2048 * 4;
constexpr size_t OFF_OPROJ = OFF_OGB + (size_t)1024 * 2048 * 2;
constexpr size_t OFF_X1    = OFF_OPROJ + (size_t)1024 * 2048 * 4;
constexpr size_t OFF_H2B   = OFF_X1 + (size_t)1024 * 2048 * 4;
constexpr size_t OFF_MLP1   = A0;
constexpr size_t OFF_MID    = A0 + (size_t)1024 * 16384 * 4;
constexpr size_t OFF_MLPOUT = OFF_H2B + (size_t)1024 * 2048 * 2;
constexpr size_t OFF_QKB    = OFF_MLPOUT + (size_t)1024 * 2048 * 4;     // [1024][16] f32
constexpr size_t OFF_G4     = OFF_QKB + (size_t)1024 * 16 * 4;          // [1040][16] float4 (padded)
constexpr size_t OFF_MLPOUT2= OFF_G4 + (size_t)1040 * 16 * 16;
constexpr size_t WS_NEED    = OFF_MLPOUT2 + (size_t)1024 * 2048 * 4;

extern "C" void kernel_launch(void* const* d_in, const int* in_sizes, int n_in,
                              void* d_out, int out_size, void* d_ws, size_t ws_size,
                              hipStream_t stream) {
  (void)in_sizes; (void)n_in; (void)out_size;
  const float* x     = (const float*)d_in[0];
  const float* wq    = (const float*)d_in[1];
  const float* wk    = (const float*)d_in[2];
  const float* wv    = (const float*)d_in[3];
  const float* cq    = (const float*)d_in[4];
  const float* ck    = (const float*)d_in[5];
  const float* cv    = (const float*)d_in[6];
  const float* wfa   = (const float*)d_in[7];
  const float* wfb   = (const float*)d_in[8];
  const float* wb    = (const float*)d_in[9];
  const float* wga   = (const float*)d_in[10];
  const float* wgb   = (const float*)d_in[11];
  const float* a_log = (const float*)d_in[12];
  const float* dtb   = (const float*)d_in[13];
  const float* onw   = (const float*)d_in[14];
  const float* wo    = (const float*)d_in[15];
  const float* ln1   = (const float*)d_in[16];
  const float* ln2   = (const float*)d_in[17];
  const float* wgate = (const float*)d_in[18];
  const float* wup   = (const float*)d_in[19];
  const float* wdown = (const float*)d_in[20];
  float* out = (float*)d_out;
  char* ws = (char*)d_ws;
  if (ws_size < WS_NEED) return;

  unsigned short* wqkvT   = (unsigned short*)(ws + OFF_WQKVT);
  unsigned short* wsmallT = (unsigned short*)(ws + OFF_WSMALLT);
  unsigned short* wgbT    = (unsigned short*)(ws + OFF_WGBT);
  unsigned short* woT     = (unsigned short*)(ws + OFF_WOT);
  unsigned short* wmlp1T  = (unsigned short*)(ws + OFF_WMLP1T);
  unsigned short* wdownT  = (unsigned short*)(ws + OFF_WDOWNT);
  unsigned short* hb      = (unsigned short*)(ws + OFF_HB);
  float* projf  = (float*)(ws + OFF_PROJ);
  float* smallf = (float*)(ws + OFF_SMALL);
  float* qf     = (float*)(ws + OFF_Q);
  float* kf     = (float*)(ws + OFF_K);
  float* vf     = (float*)(ws + OFF_V);
  unsigned short* gab = (unsigned short*)(ws + OFF_GAB);
  float* gatef  = (float*)(ws + OFF_GATE);
  float* of     = (float*)(ws + OFF_O);
  unsigned short* ogb = (unsigned short*)(ws + OFF_OGB);
  float* oprojf = (float*)(ws + OFF_OPROJ);
  float* x1f    = (float*)(ws + OFF_X1);
  unsigned short* h2b = (unsigned short*)(ws + OFF_H2B);
  float* mlp1f  = (float*)(ws + OFF_MLP1);
  unsigned short* midb = (unsigned short*)(ws + OFF_MID);
  float* mlpoutf = (float*)(ws + OFF_MLPOUT);
  float* mlpout2f = (float*)(ws + OFF_MLPOUT2);
  float* qkbuf  = (float*)(ws + OFF_QKB);
  float4* g4    = (float4*)(ws + OFF_G4);

  trans_kernel<<<dim3(64, 64), 256, 0, stream>>>(wq, wqkvT, 2048, 2048);
  trans_kernel<<<dim3(64, 64), 256, 0, stream>>>(wk, wqkvT + (size_t)2048 * 2048, 2048, 2048);
  trans_kernel<<<dim3(64, 64), 256, 0, stream>>>(wv, wqkvT + (size_t)4096 * 2048, 2048, 2048);
  trans_kernel<<<dim3(4, 64), 256, 0, stream>>>(wfa, wsmallT, 2048, 128);
  trans_kernel<<<dim3(1, 64), 256, 0, stream>>>(wb, wsmallT + (size_t)128 * 2048, 2048, 16);
  trans_kernel<<<dim3(4, 64), 256, 0, stream>>>(wga, wsmallT + (size_t)144 * 2048, 2048, 128);
  trans_kernel<<<dim3(64, 4), 256, 0, stream>>>(wgb, wgbT, 128, 2048);
  trans_kernel<<<dim3(64, 64), 256, 0, stream>>>(wo, woT, 2048, 2048);
  trans_kernel<<<dim3(256, 64), 256, 0, stream>>>(wgate, wmlp1T, 2048, 8192);
  trans_kernel<<<dim3(256, 64), 256, 0, stream>>>(wup, wmlp1T + (size_t)8192 * 2048, 2048, 8192);
  trans_kernel<<<dim3(64, 256), 256, 0, stream>>>(wdown, wdownT, 8192, 2048);

  rmsnorm_bf16_kernel<<<1024, 256, 0, stream>>>(x, ln1, hb);
  gemm_bt_kernel<<<dim3(8, 48), 256, 0, stream>>>(hb, wqkvT, projf, 1024, 6144, 2048, 2048, 2048);
  gemm_bt_kernel<<<dim3(8, 3), 256, 0, stream>>>(hb, wsmallT, smallf, 1024, 272, 2048, 2048, 2048);
  conv_kernel<<<1024, 256, 0, stream>>>(projf, cq, ck, cv, qf, kf, vf, qkbuf);
  gates_kernel<<<1024, 64, 0, stream>>>(smallf, wfb, a_log, dtb, qkbuf, g4, gab);
  gemm_bt_kernel<<<dim3(8, 16), 256, 0, stream>>>(gab, wgbT, gatef, 1024, 2048, 128, 128, 128);
  scan_kernel<<<512, 64, 0, stream>>>(qf, kf, vf, g4, of);
  gate_o_kernel<<<1024, 256, 0, stream>>>(of, gatef, onw, ogb);
  gemm_bt_kernel<<<dim3(8, 16), 256, 0, stream>>>(ogb, woT, oprojf, 1024, 2048, 2048, 2048, 2048);
  add_rmsnorm_kernel<<<1024, 256, 0, stream>>>(x, oprojf, ln2, x1f, h2b);
  gemm_bt_kernel<<<dim3(8, 128), 256, 0, stream>>>(h2b, wmlp1T, mlp1f, 1024, 16384, 2048, 2048, 2048);
  swiglu_kernel<<<2048, 256, 0, stream>>>(mlp1f, midb);
  gemm_bt_kernel<<<dim3(8, 16), 256, 0, stream>>>(midb, wdownT, mlpoutf, 1024, 2048, 4096, 8192, 8192);
  gemm_bt_kernel<<<dim3(8, 16), 256, 0, stream>>>(midb + 4096, wdownT + 4096, mlpout2f, 1024, 2048, 4096, 8192, 8192);
  final_add3_kernel<<<2048, 256, 0, stream>>>(x1f, mlpoutf, mlpout2f, out);
}

// Round 5
// 944.046 us; speedup vs baseline: 1.0168x; 1.0168x over previous
//
#include <hip/hip_runtime.h>
#include <hip/hip_bf16.h>

typedef __attribute__((ext_vector_type(8))) short short8;
typedef __attribute__((ext_vector_type(4))) float f32x4;
typedef __attribute__((ext_vector_type(8))) unsigned short u16x8;
typedef __attribute__((ext_vector_type(4))) unsigned short u16x4;

// ---------- helpers ----------
__device__ __forceinline__ unsigned short f2bf(float f) {
  unsigned u = __float_as_uint(f);
  u += 0x7fffu + ((u >> 16) & 1u);          // round-to-nearest-even
  return (unsigned short)(u >> 16);
}
__device__ __forceinline__ float silu_f(float x) { return x / (1.f + __expf(-x)); }
__device__ __forceinline__ float red16(float v) {
  v += __shfl_xor(v, 1); v += __shfl_xor(v, 2);
  v += __shfl_xor(v, 4); v += __shfl_xor(v, 8);
  return v;
}
template <int CTRL>
__device__ __forceinline__ float dpp_mv(float v) {
  return __int_as_float(__builtin_amdgcn_update_dpp(0, __float_as_int(v), CTRL, 0xF, 0xF, true));
}
__device__ __forceinline__ float red16d(float v) {
  v += dpp_mv<0xB1>(v);   // quad_perm [1,0,3,2]
  v += dpp_mv<0x4E>(v);   // quad_perm [2,3,0,1]
  v += dpp_mv<0x141>(v);  // row_half_mirror
  v += dpp_mv<0x140>(v);  // row_mirror
  return v;
}
__device__ __forceinline__ void gload16(const void* g, void* l) {
  __builtin_amdgcn_global_load_lds((const __attribute__((address_space(1))) void*)g,
                                   (__attribute__((address_space(3))) void*)l, 16, 0, 0);
}

// ---------- transpose fp32 [R][C] -> bf16 [C][R] ----------
__global__ void __launch_bounds__(256) trans_kernel(const float* __restrict__ src,
                                                    unsigned short* __restrict__ dst,
                                                    int R, int C) {
  __shared__ float tile[32][33];
  const int tx = threadIdx.x & 31, ty = threadIdx.x >> 5;
  const int c = blockIdx.x * 32 + tx;
#pragma unroll
  for (int i = 0; i < 32; i += 8) {
    int r = blockIdx.y * 32 + ty + i;
    if (r < R && c < C) tile[ty + i][tx] = src[(size_t)r * C + c];
  }
  __syncthreads();
  const int rc = blockIdx.y * 32 + tx;
#pragma unroll
  for (int i = 0; i < 32; i += 8) {
    int cc = blockIdx.x * 32 + ty + i;
    if (cc < C && rc < R) dst[(size_t)cc * R + rc] = f2bf(tile[tx][ty + i]);
  }
}

// ---------- rmsnorm (D=2048) -> bf16 ----------
__global__ void __launch_bounds__(256) rmsnorm_bf16_kernel(const float* __restrict__ x,
                                                           const float* __restrict__ w,
                                                           unsigned short* __restrict__ outb) {
  const int t = blockIdx.x, tid = threadIdx.x;
  const float* xr = x + (size_t)t * 2048 + tid * 8;
  float4 v0 = *(const float4*)xr, v1 = *(const float4*)(xr + 4);
  float ss = v0.x*v0.x + v0.y*v0.y + v0.z*v0.z + v0.w*v0.w
           + v1.x*v1.x + v1.y*v1.y + v1.z*v1.z + v1.w*v1.w;
#pragma unroll
  for (int m = 1; m < 64; m <<= 1) ss += __shfl_xor(ss, m);
  __shared__ float sb[4];
  if ((tid & 63) == 0) sb[tid >> 6] = ss;
  __syncthreads();
  float rn = rsqrtf((sb[0] + sb[1] + sb[2] + sb[3]) * (1.f / 2048.f) + 1e-6f);
  const float* wr = w + tid * 8;
  float4 w0 = *(const float4*)wr, w1 = *(const float4*)(wr + 4);
  u16x8 r;
  r[0]=f2bf(v0.x*rn*w0.x); r[1]=f2bf(v0.y*rn*w0.y); r[2]=f2bf(v0.z*rn*w0.z); r[3]=f2bf(v0.w*rn*w0.w);
  r[4]=f2bf(v1.x*rn*w1.x); r[5]=f2bf(v1.y*rn*w1.y); r[6]=f2bf(v1.z*rn*w1.z); r[7]=f2bf(v1.w*rn*w1.w);
  *(u16x8*)(outb + (size_t)t * 2048 + tid * 8) = r;
}

// ---------- x1 = x + y1 + y2 ; h2b = bf16(rmsnorm(x1)*w) ----------
__global__ void __launch_bounds__(256) add3_rmsnorm_kernel(const float* __restrict__ x,
                                                           const float* __restrict__ y1,
                                                           const float* __restrict__ y2,
                                                           const float* __restrict__ w,
                                                           float* __restrict__ x1,
                                                           unsigned short* __restrict__ h2b) {
  const int t = blockIdx.x, tid = threadIdx.x;
  const int c = tid * 8;
  const float* xr = x + (size_t)t * 2048 + c;
  const float* yr = y1 + (size_t)t * 2048 + c;
  const float* zr = y2 + (size_t)t * 2048 + c;
  float s[8]; float ss = 0.f;
  float4 a0 = *(const float4*)xr, a1 = *(const float4*)(xr + 4);
  float4 b0 = *(const float4*)yr, b1 = *(const float4*)(yr + 4);
  float4 c0 = *(const float4*)zr, c1 = *(const float4*)(zr + 4);
  s[0]=a0.x+b0.x+c0.x; s[1]=a0.y+b0.y+c0.y; s[2]=a0.z+b0.z+c0.z; s[3]=a0.w+b0.w+c0.w;
  s[4]=a1.x+b1.x+c1.x; s[5]=a1.y+b1.y+c1.y; s[6]=a1.z+b1.z+c1.z; s[7]=a1.w+b1.w+c1.w;
#pragma unroll
  for (int j = 0; j < 8; j++) ss += s[j] * s[j];
#pragma unroll
  for (int m = 1; m < 64; m <<= 1) ss += __shfl_xor(ss, m);
  __shared__ float sb[4];
  if ((tid & 63) == 0) sb[tid >> 6] = ss;
  __syncthreads();
  float rn = rsqrtf((sb[0] + sb[1] + sb[2] + sb[3]) * (1.f / 2048.f) + 1e-6f);
  float* xo = x1 + (size_t)t * 2048 + c;
  *(float4*)xo = *(float4*)&s[0];
  *(float4*)(xo + 4) = *(float4*)&s[4];
  const float* wr = w + c;
  float4 w0 = *(const float4*)wr, w1 = *(const float4*)(wr + 4);
  float wv[8] = {w0.x,w0.y,w0.z,w0.w,w1.x,w1.y,w1.z,w1.w};
  u16x8 r;
#pragma unroll
  for (int j = 0; j < 8; j++) r[j] = f2bf(s[j] * rn * wv[j]);
  *(u16x8*)(h2b + (size_t)t * 2048 + c) = r;
}

// ---------- bf16 GEMM: C[M,N] = A[M,K] * Bt[N,K]^T  (m97-style, strided) ----------
__global__ void __launch_bounds__(256) gemm_bt_kernel(const unsigned short* __restrict__ A,
                                                      const unsigned short* __restrict__ Bt,
                                                      float* __restrict__ C,
                                                      int M, int N, int K, int lda, int ldb) {
  __shared__ unsigned short As[128][32];
  __shared__ unsigned short Bs[128][32];
  const int tid = threadIdx.x;
  const int m0 = blockIdx.x << 7, n0 = blockIdx.y << 7;
  const int wave = tid >> 6, lane = tid & 63;
  const int wm = (wave >> 1) << 6, wn = (wave & 1) << 6;
  const int lrow = lane >> 2, lcol = lane & 3;
  const int ar0 = wave * 16 + lrow;
  const int ar1 = ar0 + 64;
  int br0 = n0 + ar0; br0 = br0 < N ? br0 : N - 1;
  int br1 = n0 + ar1; br1 = br1 < N ? br1 : N - 1;
  const unsigned short* Aptr0 = A + (size_t)(m0 + ar0) * lda + ((lcol ^ (ar0 & 3)) << 3);
  const unsigned short* Aptr1 = A + (size_t)(m0 + ar1) * lda + ((lcol ^ (ar1 & 3)) << 3);
  const unsigned short* Bptr0 = Bt + (size_t)br0 * ldb + ((lcol ^ (ar0 & 3)) << 3);
  const unsigned short* Bptr1 = Bt + (size_t)br1 * ldb + ((lcol ^ (ar1 & 3)) << 3);
  unsigned short* lA0 = &As[wave * 16][0];
  unsigned short* lA1 = &As[64 + wave * 16][0];
  unsigned short* lB0 = &Bs[wave * 16][0];
  unsigned short* lB1 = &Bs[64 + wave * 16][0];
  const int frow = lane & 15, fkb = lane >> 4;
  f32x4 acc[4][4];
#pragma unroll
  for (int i = 0; i < 4; i++)
#pragma unroll
    for (int j = 0; j < 4; j++) acc[i][j] = (f32x4){0.f, 0.f, 0.f, 0.f};

  for (int k0 = 0; k0 < K; k0 += 32) {
    gload16(Aptr0 + k0, lA0);
    gload16(Aptr1 + k0, lA1);
    gload16(Bptr0 + k0, lB0);
    gload16(Bptr1 + k0, lB1);
    __syncthreads();
    short8 af[4], bfr[4];
#pragma unroll
    for (int i = 0; i < 4; i++) {
      int ra = wm + i * 16 + frow;
      af[i] = *(const short8*)&As[ra][(fkb ^ (ra & 3)) << 3];
      int rb = wn + i * 16 + frow;
      bfr[i] = *(const short8*)&Bs[rb][(fkb ^ (rb & 3)) << 3];
    }
#pragma unroll
    for (int i = 0; i < 4; i++)
#pragma unroll
      for (int j = 0; j < 4; j++)
        acc[i][j] = __builtin_amdgcn_mfma_f32_16x16x32_bf16(af[i], bfr[j], acc[i][j], 0, 0, 0);
    __syncthreads();
  }
  const int crow = (lane >> 4) << 2, ccol = lane & 15;
#pragma unroll
  for (int i = 0; i < 4; i++) {
    const int gr = m0 + wm + i * 16 + crow;
#pragma unroll
    for (int j = 0; j < 4; j++) {
      const int gc = n0 + wn + j * 16 + ccol;
      if (gc < N) {
#pragma unroll
        for (int r = 0; r < 4; r++) C[(size_t)(gr + r) * N + gc] = acc[i][j][r];
      }
    }
  }
}

// ---------- causal dwconv(K=4) + silu + per-head l2norm + qk dot ----------
__global__ void __launch_bounds__(256) conv_kernel(const float* __restrict__ proj,
                                                   const float* __restrict__ cq,
                                                   const float* __restrict__ ck,
                                                   const float* __restrict__ cv,
                                                   float* __restrict__ q, float* __restrict__ k,
                                                   float* __restrict__ v,
                                                   float* __restrict__ qkbuf) {
  const int t = blockIdx.x, tid = threadIdx.x;
  const int c = tid << 3;
  float aq[8] = {0,0,0,0,0,0,0,0}, ak[8] = {0,0,0,0,0,0,0,0}, av[8] = {0,0,0,0,0,0,0,0};
#pragma unroll
  for (int i = 0; i < 4; i++) {
    const int tt = t + i - 3;
    if (tt < 0) continue;
    const float* pr = proj + (size_t)tt * 6144;
    float pq[8], pk[8], pv[8], w0[8], w1[8], w2[8];
    *(float4*)&pq[0] = *(const float4*)(pr + c);        *(float4*)&pq[4] = *(const float4*)(pr + c + 4);
    *(float4*)&pk[0] = *(const float4*)(pr + 2048 + c); *(float4*)&pk[4] = *(const float4*)(pr + 2048 + c + 4);
    *(float4*)&pv[0] = *(const float4*)(pr + 4096 + c); *(float4*)&pv[4] = *(const float4*)(pr + 4096 + c + 4);
    *(float4*)&w0[0] = *(const float4*)(cq + i * 2048 + c); *(float4*)&w0[4] = *(const float4*)(cq + i * 2048 + c + 4);
    *(float4*)&w1[0] = *(const float4*)(ck + i * 2048 + c); *(float4*)&w1[4] = *(const float4*)(ck + i * 2048 + c + 4);
    *(float4*)&w2[0] = *(const float4*)(cv + i * 2048 + c); *(float4*)&w2[4] = *(const float4*)(cv + i * 2048 + c + 4);
#pragma unroll
    for (int j = 0; j < 8; j++) { aq[j] += w0[j]*pq[j]; ak[j] += w1[j]*pk[j]; av[j] += w2[j]*pv[j]; }
  }
  float sq[8], sk[8], sv[8]; float ssq = 0.f, ssk = 0.f;
#pragma unroll
  for (int j = 0; j < 8; j++) {
    sq[j] = silu_f(aq[j]); ssq += sq[j]*sq[j];
    sk[j] = silu_f(ak[j]); ssk += sk[j]*sk[j];
    sv[j] = silu_f(av[j]);
  }
  ssq = red16(ssq); ssk = red16(ssk);
  const float rq = rsqrtf(ssq + 1e-6f) * 0.08838834764831845f;  // * DK^-0.5
  const float rk = rsqrtf(ssk + 1e-6f);
  float oq[8], ok[8]; float qkl = 0.f;
#pragma unroll
  for (int j = 0; j < 8; j++) { oq[j] = sq[j]*rq; ok[j] = sk[j]*rk; qkl += oq[j]*ok[j]; }
  qkl = red16(qkl);
  if ((tid & 15) == 0) qkbuf[(size_t)t * 16 + (tid >> 4)] = qkl;
  float* qo = q + (size_t)t * 2048 + c;
  *(float4*)qo = *(float4*)&oq[0]; *(float4*)(qo + 4) = *(float4*)&oq[4];
  float* ko = k + (size_t)t * 2048 + c;
  *(float4*)ko = *(float4*)&ok[0]; *(float4*)(ko + 4) = *(float4*)&ok[4];
  float* vo = v + (size_t)t * 2048 + c;
  *(float4*)vo = *(float4*)&sv[0]; *(float4*)(vo + 4) = *(float4*)&sv[4];
}

// ---------- packed gates: g4[t][h] = (eg, beta, qk, 0); gab->bf16 ----------
__global__ void __launch_bounds__(64) gates_kernel(const float* __restrict__ small,
                                                   const float* __restrict__ wfb,
                                                   const float* __restrict__ a_log,
                                                   const float* __restrict__ dtb,
                                                   const float* __restrict__ qkbuf,
                                                   float4* __restrict__ g4,
                                                   unsigned short* __restrict__ gab) {
  const int t = blockIdx.x, tid = threadIdx.x;
  const float* srow = small + (size_t)t * 272;
  if (tid < 16) {
    float d = dtb[tid];
    for (int j = 0; j < 128; j++) d += srow[j] * wfb[j * 16 + tid];
    float sp = (d > 20.f) ? d : log1pf(expf(d));
    float eg = expf(-expf(a_log[tid]) * sp);
    float b = srow[128 + tid];
    float bt = 1.f / (1.f + expf(-b));
    g4[t * 16 + tid] = make_float4(eg, bt, qkbuf[t * 16 + tid], 0.f);
  }
  for (int j = tid; j < 128; j += 64) gab[(size_t)t * 128 + j] = f2bf(srow[144 + j]);
}

// ---------- pack per-(head,slice) aux stream: {eg,bt,qk,0, v0,v1,v2,v3} ----------
__global__ void __launch_bounds__(64) pack_aux_kernel(const float* __restrict__ v,
                                                      const float4* __restrict__ g4,
                                                      float* __restrict__ paux) {
  const int pair = blockIdx.x;         // 512 = h*32 + slice
  const int h = pair >> 5, vbase = (pair & 31) << 2;
  for (int t = threadIdx.x; t < 1024; t += 64) {
    float4 g = g4[t * 16 + h];
    float4 vv = *(const float4*)(v + (size_t)t * 2048 + h * 128 + vbase);
    float* w = paux + ((size_t)pair * 1024 + t) * 8;
    *(float4*)w = make_float4(g.x, g.y, g.z, 0.f);
    *(float4*)(w + 4) = vv;
  }
}

// ---------- gated delta-rule scan v3 ----------
// global->LDS counted-vmcnt pipeline (depth 2 chunks) PLUS in-chunk 2-deep
// register pipeline over the LDS reads (named A/B regs + sched_barrier fences).
struct StepRegs { float4 k0, k1, q0, q1, ga; float vv; };

__device__ __forceinline__ void lds_step(StepRegs& R, const float* buf, const float* aux,
                                         int i, int kl, int vl) {
  const float* sp = buf + i * 256 + kl * 8;
  R.k0 = *(const float4*)sp;         R.k1 = *(const float4*)(sp + 4);
  R.q0 = *(const float4*)(sp + 128); R.q1 = *(const float4*)(sp + 132);
  const float* ax = aux + i * 8;
  R.ga = *(const float4*)ax;
  R.vv = ax[4 + vl];
}

__device__ __forceinline__ void do_step(const StepRegs& X, float (&S)[8], float* ob,
                                        bool dostore, int tt) {
  const float eg = X.ga.x, bt = X.ga.y, qk = X.ga.z;
  float a0 = fmaf(X.k1.x, S[4], X.k0.x * S[0]);
  float a1 = fmaf(X.k1.y, S[5], X.k0.y * S[1]);
  float a2 = fmaf(X.k1.z, S[6], X.k0.z * S[2]);
  float a3 = fmaf(X.k1.w, S[7], X.k0.w * S[3]);
  float b0 = fmaf(X.q1.x, S[4], X.q0.x * S[0]);
  float b1 = fmaf(X.q1.y, S[5], X.q0.y * S[1]);
  float b2 = fmaf(X.q1.z, S[6], X.q0.z * S[2]);
  float b3 = fmaf(X.q1.w, S[7], X.q0.w * S[3]);
  float kS = red16d((a0 + a1) + (a2 + a3));
  float qS = red16d((b0 + b1) + (b2 + b3));
  float delta = fmaf(-(bt * eg), kS, bt * X.vv);   // bt*(v - eg*kS)
  S[0] = fmaf(X.k0.x, delta, eg * S[0]);
  S[1] = fmaf(X.k0.y, delta, eg * S[1]);
  S[2] = fmaf(X.k0.z, delta, eg * S[2]);
  S[3] = fmaf(X.k0.w, delta, eg * S[3]);
  S[4] = fmaf(X.k1.x, delta, eg * S[4]);
  S[5] = fmaf(X.k1.y, delta, eg * S[5]);
  S[6] = fmaf(X.k1.z, delta, eg * S[6]);
  S[7] = fmaf(X.k1.w, delta, eg * S[7]);
  if (dostore) ob[(size_t)tt * 2048] = fmaf(qk, delta, eg * qS);
}

__device__ __forceinline__ void stage3(const float* kb, const float* qb, const float* auxb,
                                       int tbase, float* bkq, float* baux, int lane) {
  const int l32 = lane & 31;
  const float* g = (lane < 32 ? kb : qb) + l32 * 4;
#pragma unroll
  for (int i = 0; i < 8; i++) {
    int t = (tbase + i) & 1023;
    gload16(g + (size_t)t * 2048, bkq + i * 256);
  }
  const int tb = tbase & 1023;
  if (lane < 16) gload16(auxb + tb * 8 + lane * 4, baux);
}

#define SB0() __builtin_amdgcn_sched_barrier(0)

__device__ __forceinline__ void compute_chunk(const float* buf, const float* aux,
                                              int tbase, float (&S)[8], float* ob,
                                              bool dostore, int kl, int vl) {
  StepRegs A, B;
  lds_step(A, buf, aux, 0, kl, vl);
  lds_step(B, buf, aux, 1, kl, vl); SB0();
  do_step(A, S, ob, dostore, tbase + 0);
  lds_step(A, buf, aux, 2, kl, vl); SB0();
  do_step(B, S, ob, dostore, tbase + 1);
  lds_step(B, buf, aux, 3, kl, vl); SB0();
  do_step(A, S, ob, dostore, tbase + 2);
  lds_step(A, buf, aux, 4, kl, vl); SB0();
  do_step(B, S, ob, dostore, tbase + 3);
  lds_step(B, buf, aux, 5, kl, vl); SB0();
  do_step(A, S, ob, dostore, tbase + 4);
  lds_step(A, buf, aux, 6, kl, vl); SB0();
  do_step(B, S, ob, dostore, tbase + 5);
  lds_step(B, buf, aux, 7, kl, vl); SB0();
  do_step(A, S, ob, dostore, tbase + 6);
  SB0();
  do_step(B, S, ob, dostore, tbase + 7);
}

__global__ void __launch_bounds__(64, 1) scan_kernel(const float* __restrict__ q,
                                                     const float* __restrict__ k,
                                                     const float* __restrict__ paux,
                                                     float* __restrict__ o) {
  __shared__ float lkq[3][2048];    // 3 chunks x 8 steps x (128 k | 128 q)
  __shared__ float laux[3][64];     // 3 chunks x 8 steps x 8 floats
  const int b = blockIdx.x;         // 512 = 16 heads * 32 slices
  const int xcd = b & 7, r = b >> 3;
  const int h = (xcd << 1) | (r >> 5);
  const int slice = r & 31;
  const int pair = h * 32 + slice;
  const int vbase = slice << 2;
  const int lane = threadIdx.x;
  const int kl = lane & 15, vl = lane >> 4;
  const float* kb = k + h * 128;
  const float* qb = q + h * 128;
  const float* auxb = paux + (size_t)pair * 8192;
  float* ob = o + h * 128 + vbase + vl;
  const bool dostore = (kl == 0);
  float* b0 = &lkq[0][0]; float* b1 = &lkq[1][0]; float* b2 = &lkq[2][0];
  float* x0 = &laux[0][0]; float* x1 = &laux[1][0]; float* x2 = &laux[2][0];
  stage3(kb, qb, auxb, 0, b0, x0, lane);
  stage3(kb, qb, auxb, 8, b1, x1, lane);
  asm volatile("s_waitcnt vmcnt(9)" ::: "memory");   // chunk0 resident
  SB0();
  float S[8] = {0, 0, 0, 0, 0, 0, 0, 0};
  for (int c = 0; c < 128; c++) {
    stage3(kb, qb, auxb, (c + 2) * 8, b2, x2, lane);   // prefetch depth 2
    compute_chunk(b0, x0, c * 8, S, ob, dostore, kl, vl);
    // youngest 17 = 9 prefetch loads + 8 o-stores -> waits chunk c+1 loads
    asm volatile("s_waitcnt vmcnt(17)" ::: "memory");
    SB0();
    float* tb = b0; b0 = b1; b1 = b2; b2 = tb;
    float* tx = x0; x0 = x1; x1 = x2; x2 = tx;
  }
}

// ---------- o_gated = bf16(rmsnorm_head(o)*w * silu(gate)) ----------
__global__ void __launch_bounds__(256) gate_o_kernel(const float* __restrict__ o,
                                                     const float* __restrict__ gate,
                                                     const float* __restrict__ onw,
                                                     unsigned short* __restrict__ ogb) {
  const int t = blockIdx.x, tid = threadIdx.x;
  const int c = tid << 3;
  const float* orow = o + (size_t)t * 2048 + c;
  float ov[8]; *(float4*)&ov[0] = *(const float4*)orow; *(float4*)&ov[4] = *(const float4*)(orow + 4);
  float ss = 0.f;
#pragma unroll
  for (int j = 0; j < 8; j++) ss += ov[j] * ov[j];
  ss = red16(ss);
  const float rn = rsqrtf(ss * (1.f / 128.f) + 1e-6f);
  const int dv = (tid & 15) << 3;
  float wv[8]; *(float4*)&wv[0] = *(const float4*)(onw + dv); *(float4*)&wv[4] = *(const float4*)(onw + dv + 4);
  const float* grow = gate + (size_t)t * 2048 + c;
  float gv[8]; *(float4*)&gv[0] = *(const float4*)grow; *(float4*)&gv[4] = *(const float4*)(grow + 4);
  u16x8 r;
#pragma unroll
  for (int j = 0; j < 8; j++) r[j] = f2bf(ov[j] * rn * wv[j] * silu_f(gv[j]));
  *(u16x8*)(ogb + (size_t)t * 2048 + c) = r;
}

// ---------- swiglu ----------
__global__ void swiglu_kernel(const float* __restrict__ m1, unsigned short* __restrict__ mid) {
  const int NU = 1024 * 2048;
  for (int u = blockIdx.x * blockDim.x + threadIdx.x; u < NU; u += gridDim.x * blockDim.x) {
    const int t = u >> 11;
    const int j4 = (u & 2047) << 2;
    const float* base = m1 + (size_t)t * 16384;
    float4 gv = *(const float4*)(base + j4);
    float4 uv = *(const float4*)(base + 8192 + j4);
    u16x4 r;
    r[0] = f2bf(silu_f(gv.x) * uv.x);
    r[1] = f2bf(silu_f(gv.y) * uv.y);
    r[2] = f2bf(silu_f(gv.z) * uv.z);
    r[3] = f2bf(silu_f(gv.w) * uv.w);
    *(u16x4*)(mid + (size_t)t * 8192 + j4) = r;
  }
}

// ---------- out = a + b + c ----------
__global__ void final_add3_kernel(const float* __restrict__ a, const float* __restrict__ b,
                                  const float* __restrict__ c, float* __restrict__ out) {
  const int NU = 1024 * 512;
  for (int u = blockIdx.x * blockDim.x + threadIdx.x; u < NU; u += gridDim.x * blockDim.x) {
    float4 va = ((const float4*)a)[u];
    float4 vb = ((const float4*)b)[u];
    float4 vc = ((const float4*)c)[u];
    va.x += vb.x + vc.x; va.y += vb.y + vc.y; va.z += vb.z + vc.z; va.w += vb.w + vc.w;
    ((float4*)out)[u] = va;
  }
}

// ---------- ws layout (bytes) ----------
constexpr size_t SZ_WQKVT   = (size_t)6144 * 2048 * 2;
constexpr size_t SZ_WSMALLT = (size_t)272 * 2048 * 2;
constexpr size_t SZ_WGBT    = (size_t)2048 * 128 * 2;
constexpr size_t SZ_WOT     = (size_t)2048 * 2048 * 2;
constexpr size_t SZ_WMLP1T  = (size_t)16384 * 2048 * 2;
constexpr size_t SZ_WDOWNT  = (size_t)2048 * 8192 * 2;
constexpr size_t OFF_WQKVT   = 0;
constexpr size_t OFF_WSMALLT = OFF_WQKVT + SZ_WQKVT;
constexpr size_t OFF_WGBT    = OFF_WSMALLT + SZ_WSMALLT;
constexpr size_t OFF_WOT     = OFF_WGBT + SZ_WGBT;
constexpr size_t OFF_WMLP1T  = OFF_WOT + SZ_WOT;
constexpr size_t OFF_WDOWNT  = OFF_WMLP1T + SZ_WMLP1T;
constexpr size_t A0          = OFF_WDOWNT + SZ_WDOWNT;
constexpr size_t OFF_HB    = A0;
constexpr size_t OFF_PROJ  = OFF_HB + (size_t)1024 * 2048 * 2;
constexpr size_t OFF_SMALL = OFF_PROJ + (size_t)1024 * 6144 * 4;
constexpr size_t OFF_Q     = OFF_SMALL + (size_t)1024 * 272 * 4;
constexpr size_t OFF_K     = OFF_Q + (size_t)1024 * 2048 * 4;
constexpr size_t OFF_V     = OFF_K + (size_t)1024 * 2048 * 4;
constexpr size_t OFF_G     = OFF_V + (size_t)1024 * 2048 * 4;
constexpr size_t OFF_BETA  = OFF_G + (size_t)1024 * 16 * 4;
constexpr size_t OFF_GAB   = OFF_BETA + (size_t)1024 * 16 * 4;
constexpr size_t OFF_GATE  = OFF_GAB + (size_t)1024 * 128 * 2;
constexpr size_t OFF_O     = OFF_GATE + (size_t)1024 * 2048 * 4;
constexpr size_t OFF_OGB   = OFF_O + (size_t)1024 * 2048 * 4;
constexpr size_t OFF_OPROJ = OFF_OGB + (size_t)1024 * 2048 * 2;
constexpr size_t OFF_X1    = OFF_OPROJ + (size_t)1024 * 2048 * 4;
constexpr size_t OFF_H2B   = OFF_X1 + (size_t)1024 * 2048 * 4;
constexpr size_t OFF_MLP1   = A0;
constexpr size_t OFF_MID    = A0 + (size_t)1024 * 16384 * 4;
constexpr size_t OFF_MLPOUT = OFF_H2B + (size_t)1024 * 2048 * 2;
constexpr size_t OFF_QKB    = OFF_MLPOUT + (size_t)1024 * 2048 * 4;     // [1024][16] f32
constexpr size_t OFF_G4     = OFF_QKB + (size_t)1024 * 16 * 4;          // [1040][16] float4
constexpr size_t OFF_MLPOUT2= OFF_G4 + (size_t)1040 * 16 * 16;
constexpr size_t WS_NEED    = OFF_MLPOUT2 + (size_t)1024 * 2048 * 4;
// aliases (liveness): paux sits in dead projf (16MB <= 24MB); oproj2 in dead `of`.
constexpr size_t OFF_PAUX   = OFF_PROJ;
constexpr size_t OFF_OPROJ2 = OFF_O;

extern "C" void kernel_launch(void* const* d_in, const int* in_sizes, int n_in,
                              void* d_out, int out_size, void* d_ws, size_t ws_size,
                              hipStream_t stream) {
  (void)in_sizes; (void)n_in; (void)out_size;
  const float* x     = (const float*)d_in[0];
  const float* wq    = (const float*)d_in[1];
  const float* wk    = (const float*)d_in[2];
  const float* wv    = (const float*)d_in[3];
  const float* cq    = (const float*)d_in[4];
  const float* ck    = (const float*)d_in[5];
  const float* cv    = (const float*)d_in[6];
  const float* wfa   = (const float*)d_in[7];
  const float* wfb   = (const float*)d_in[8];
  const float* wb    = (const float*)d_in[9];
  const float* wga   = (const float*)d_in[10];
  const float* wgb   = (const float*)d_in[11];
  const float* a_log = (const float*)d_in[12];
  const float* dtb   = (const float*)d_in[13];
  const float* onw   = (const float*)d_in[14];
  const float* wo    = (const float*)d_in[15];
  const float* ln1   = (const float*)d_in[16];
  const float* ln2   = (const float*)d_in[17];
  const float* wgate = (const float*)d_in[18];
  const float* wup   = (const float*)d_in[19];
  const float* wdown = (const float*)d_in[20];
  float* out = (float*)d_out;
  char* ws = (char*)d_ws;
  if (ws_size < WS_NEED) return;

  unsigned short* wqkvT   = (unsigned short*)(ws + OFF_WQKVT);
  unsigned short* wsmallT = (unsigned short*)(ws + OFF_WSMALLT);
  unsigned short* wgbT    = (unsigned short*)(ws + OFF_WGBT);
  unsigned short* woT     = (unsigned short*)(ws + OFF_WOT);
  unsigned short* wmlp1T  = (unsigned short*)(ws + OFF_WMLP1T);
  unsigned short* wdownT  = (unsigned short*)(ws + OFF_WDOWNT);
  unsigned short* hb      = (unsigned short*)(ws + OFF_HB);
  float* projf  = (float*)(ws + OFF_PROJ);
  float* smallf = (float*)(ws + OFF_SMALL);
  float* qf     = (float*)(ws + OFF_Q);
  float* kf     = (float*)(ws + OFF_K);
  float* vf     = (float*)(ws + OFF_V);
  unsigned short* gab = (unsigned short*)(ws + OFF_GAB);
  float* gatef  = (float*)(ws + OFF_GATE);
  float* of     = (float*)(ws + OFF_O);
  unsigned short* ogb = (unsigned short*)(ws + OFF_OGB);
  float* oprojf = (float*)(ws + OFF_OPROJ);
  float* oproj2f= (float*)(ws + OFF_OPROJ2);
  float* x1f    = (float*)(ws + OFF_X1);
  unsigned short* h2b = (unsigned short*)(ws + OFF_H2B);
  float* mlp1f  = (float*)(ws + OFF_MLP1);
  unsigned short* midb = (unsigned short*)(ws + OFF_MID);
  float* mlpoutf = (float*)(ws + OFF_MLPOUT);
  float* mlpout2f = (float*)(ws + OFF_MLPOUT2);
  float* qkbuf  = (float*)(ws + OFF_QKB);
  float4* g4    = (float4*)(ws + OFF_G4);
  float* paux   = (float*)(ws + OFF_PAUX);

  trans_kernel<<<dim3(64, 64), 256, 0, stream>>>(wq, wqkvT, 2048, 2048);
  trans_kernel<<<dim3(64, 64), 256, 0, stream>>>(wk, wqkvT + (size_t)2048 * 2048, 2048, 2048);
  trans_kernel<<<dim3(64, 64), 256, 0, stream>>>(wv, wqkvT + (size_t)4096 * 2048, 2048, 2048);
  trans_kernel<<<dim3(4, 64), 256, 0, stream>>>(wfa, wsmallT, 2048, 128);
  trans_kernel<<<dim3(1, 64), 256, 0, stream>>>(wb, wsmallT + (size_t)128 * 2048, 2048, 16);
  trans_kernel<<<dim3(4, 64), 256, 0, stream>>>(wga, wsmallT + (size_t)144 * 2048, 2048, 128);
  trans_kernel<<<dim3(64, 4), 256, 0, stream>>>(wgb, wgbT, 128, 2048);
  trans_kernel<<<dim3(64, 64), 256, 0, stream>>>(wo, woT, 2048, 2048);
  trans_kernel<<<dim3(256, 64), 256, 0, stream>>>(wgate, wmlp1T, 2048, 8192);
  trans_kernel<<<dim3(256, 64), 256, 0, stream>>>(wup, wmlp1T + (size_t)8192 * 2048, 2048, 8192);
  trans_kernel<<<dim3(64, 256), 256, 0, stream>>>(wdown, wdownT, 8192, 2048);

  rmsnorm_bf16_kernel<<<1024, 256, 0, stream>>>(x, ln1, hb);
  gemm_bt_kernel<<<dim3(8, 48), 256, 0, stream>>>(hb, wqkvT, projf, 1024, 6144, 2048, 2048, 2048);
  gemm_bt_kernel<<<dim3(8, 3), 256, 0, stream>>>(hb, wsmallT, smallf, 1024, 272, 2048, 2048, 2048);
  conv_kernel<<<1024, 256, 0, stream>>>(projf, cq, ck, cv, qf, kf, vf, qkbuf);
  gates_kernel<<<1024, 64, 0, stream>>>(smallf, wfb, a_log, dtb, qkbuf, g4, gab);
  pack_aux_kernel<<<512, 64, 0, stream>>>(vf, g4, paux);
  gemm_bt_kernel<<<dim3(8, 16), 256, 0, stream>>>(gab, wgbT, gatef, 1024, 2048, 128, 128, 128);
  scan_kernel<<<512, 64, 0, stream>>>(qf, kf, paux, of);
  gate_o_kernel<<<1024, 256, 0, stream>>>(of, gatef, onw, ogb);
  // split-K x2 output projection (K=2048 -> 2x1024, 256 blocks busy)
  gemm_bt_kernel<<<dim3(8, 16), 256, 0, stream>>>(ogb, woT, oprojf, 1024, 2048, 1024, 2048, 2048);
  gemm_bt_kernel<<<dim3(8, 16), 256, 0, stream>>>(ogb + 1024, woT + 1024, oproj2f, 1024, 2048, 1024, 2048, 2048);
  add3_rmsnorm_kernel<<<1024, 256, 0, stream>>>(x, oprojf, oproj2f, ln2, x1f, h2b);
  gemm_bt_kernel<<<dim3(8, 128), 256, 0, stream>>>(h2b, wmlp1T, mlp1f, 1024, 16384, 2048, 2048, 2048);
  swiglu_kernel<<<2048, 256, 0, stream>>>(mlp1f, midb);
  gemm_bt_kernel<<<dim3(8, 16), 256, 0, stream>>>(midb, wdownT, mlpoutf, 1024, 2048, 4096, 8192, 8192);
  gemm_bt_kernel<<<dim3(8, 16), 256, 0, stream>>>(midb + 4096, wdownT + 4096, mlpout2f, 1024, 2048, 4096, 8192, 8192);
  final_add3_kernel<<<2048, 256, 0, stream>>>(x1f, mlpoutf, mlpout2f, out);
}

// Round 8
// 925.378 us; speedup vs baseline: 1.0374x; 1.0202x over previous
//
#include <hip/hip_runtime.h>
#include <hip/hip_bf16.h>

typedef __attribute__((ext_vector_type(8))) short short8;
typedef __attribute__((ext_vector_type(4))) float f32x4;
typedef __attribute__((ext_vector_type(8))) unsigned short u16x8;
typedef __attribute__((ext_vector_type(4))) unsigned short u16x4;

// ---------- helpers ----------
__device__ __forceinline__ unsigned short f2bf(float f) {
  unsigned u = __float_as_uint(f);
  u += 0x7fffu + ((u >> 16) & 1u);          // round-to-nearest-even
  return (unsigned short)(u >> 16);
}
__device__ __forceinline__ float silu_f(float x) { return x / (1.f + __expf(-x)); }
__device__ __forceinline__ float red16(float v) {
  v += __shfl_xor(v, 1); v += __shfl_xor(v, 2);
  v += __shfl_xor(v, 4); v += __shfl_xor(v, 8);
  return v;
}
template <int CTRL>
__device__ __forceinline__ float dpp_mv(float v) {
  return __int_as_float(__builtin_amdgcn_update_dpp(0, __float_as_int(v), CTRL, 0xF, 0xF, true));
}
__device__ __forceinline__ float red16d(float v) {
  v += dpp_mv<0xB1>(v);   // quad_perm [1,0,3,2]
  v += dpp_mv<0x4E>(v);   // quad_perm [2,3,0,1]
  v += dpp_mv<0x141>(v);  // row_half_mirror
  v += dpp_mv<0x140>(v);  // row_mirror
  return v;
}
__device__ __forceinline__ void gload16(const void* g, void* l) {
  __builtin_amdgcn_global_load_lds((const __attribute__((address_space(1))) void*)g,
                                   (__attribute__((address_space(3))) void*)l, 16, 0, 0);
}

// ---------- transpose fp32 [R][C] -> bf16 [C][R] ----------
__global__ void __launch_bounds__(256) trans_kernel(const float* __restrict__ src,
                                                    unsigned short* __restrict__ dst,
                                                    int R, int C) {
  __shared__ float tile[32][33];
  const int tx = threadIdx.x & 31, ty = threadIdx.x >> 5;
  const int c = blockIdx.x * 32 + tx;
#pragma unroll
  for (int i = 0; i < 32; i += 8) {
    int r = blockIdx.y * 32 + ty + i;
    if (r < R && c < C) tile[ty + i][tx] = src[(size_t)r * C + c];
  }
  __syncthreads();
  const int rc = blockIdx.y * 32 + tx;
#pragma unroll
  for (int i = 0; i < 32; i += 8) {
    int cc = blockIdx.x * 32 + ty + i;
    if (cc < C && rc < R) dst[(size_t)cc * R + rc] = f2bf(tile[tx][ty + i]);
  }
}

// ---------- rmsnorm (D=2048) -> bf16 ----------
__global__ void __launch_bounds__(256) rmsnorm_bf16_kernel(const float* __restrict__ x,
                                                           const float* __restrict__ w,
                                                           unsigned short* __restrict__ outb) {
  const int t = blockIdx.x, tid = threadIdx.x;
  const float* xr = x + (size_t)t * 2048 + tid * 8;
  float4 v0 = *(const float4*)xr, v1 = *(const float4*)(xr + 4);
  float ss = v0.x*v0.x + v0.y*v0.y + v0.z*v0.z + v0.w*v0.w
           + v1.x*v1.x + v1.y*v1.y + v1.z*v1.z + v1.w*v1.w;
#pragma unroll
  for (int m = 1; m < 64; m <<= 1) ss += __shfl_xor(ss, m);
  __shared__ float sb[4];
  if ((tid & 63) == 0) sb[tid >> 6] = ss;
  __syncthreads();
  float rn = rsqrtf((sb[0] + sb[1] + sb[2] + sb[3]) * (1.f / 2048.f) + 1e-6f);
  const float* wr = w + tid * 8;
  float4 w0 = *(const float4*)wr, w1 = *(const float4*)(wr + 4);
  u16x8 r;
  r[0]=f2bf(v0.x*rn*w0.x); r[1]=f2bf(v0.y*rn*w0.y); r[2]=f2bf(v0.z*rn*w0.z); r[3]=f2bf(v0.w*rn*w0.w);
  r[4]=f2bf(v1.x*rn*w1.x); r[5]=f2bf(v1.y*rn*w1.y); r[6]=f2bf(v1.z*rn*w1.z); r[7]=f2bf(v1.w*rn*w1.w);
  *(u16x8*)(outb + (size_t)t * 2048 + tid * 8) = r;
}

// ---------- x1 = x + y1 + y2 ; h2b = bf16(rmsnorm(x1)*w) ----------
__global__ void __launch_bounds__(256) add3_rmsnorm_kernel(const float* __restrict__ x,
                                                           const float* __restrict__ y1,
                                                           const float* __restrict__ y2,
                                                           const float* __restrict__ w,
                                                           float* __restrict__ x1,
                                                           unsigned short* __restrict__ h2b) {
  const int t = blockIdx.x, tid = threadIdx.x;
  const int c = tid * 8;
  const float* xr = x + (size_t)t * 2048 + c;
  const float* yr = y1 + (size_t)t * 2048 + c;
  const float* zr = y2 + (size_t)t * 2048 + c;
  float s[8]; float ss = 0.f;
  float4 a0 = *(const float4*)xr, a1 = *(const float4*)(xr + 4);
  float4 b0 = *(const float4*)yr, b1 = *(const float4*)(yr + 4);
  float4 c0 = *(const float4*)zr, c1 = *(const float4*)(zr + 4);
  s[0]=a0.x+b0.x+c0.x; s[1]=a0.y+b0.y+c0.y; s[2]=a0.z+b0.z+c0.z; s[3]=a0.w+b0.w+c0.w;
  s[4]=a1.x+b1.x+c1.x; s[5]=a1.y+b1.y+c1.y; s[6]=a1.z+b1.z+c1.z; s[7]=a1.w+b1.w+c1.w;
#pragma unroll
  for (int j = 0; j < 8; j++) ss += s[j] * s[j];
#pragma unroll
  for (int m = 1; m < 64; m <<= 1) ss += __shfl_xor(ss, m);
  __shared__ float sb[4];
  if ((tid & 63) == 0) sb[tid >> 6] = ss;
  __syncthreads();
  float rn = rsqrtf((sb[0] + sb[1] + sb[2] + sb[3]) * (1.f / 2048.f) + 1e-6f);
  float* xo = x1 + (size_t)t * 2048 + c;
  *(float4*)xo = *(float4*)&s[0];
  *(float4*)(xo + 4) = *(float4*)&s[4];
  const float* wr = w + c;
  float4 w0 = *(const float4*)wr, w1 = *(const float4*)(wr + 4);
  float wv[8] = {w0.x,w0.y,w0.z,w0.w,w1.x,w1.y,w1.z,w1.w};
  u16x8 r;
#pragma unroll
  for (int j = 0; j < 8; j++) r[j] = f2bf(s[j] * rn * wv[j]);
  *(u16x8*)(h2b + (size_t)t * 2048 + c) = r;
}

// ---------- bf16 GEMM: C[M,N] = A[M,K] * Bt[N,K]^T  (m97-style, strided) ----------
__global__ void __launch_bounds__(256) gemm_bt_kernel(const unsigned short* __restrict__ A,
                                                      const unsigned short* __restrict__ Bt,
                                                      float* __restrict__ C,
                                                      int M, int N, int K, int lda, int ldb) {
  __shared__ unsigned short As[128][32];
  __shared__ unsigned short Bs[128][32];
  const int tid = threadIdx.x;
  const int m0 = blockIdx.x << 7, n0 = blockIdx.y << 7;
  const int wave = tid >> 6, lane = tid & 63;
  const int wm = (wave >> 1) << 6, wn = (wave & 1) << 6;
  const int lrow = lane >> 2, lcol = lane & 3;
  const int ar0 = wave * 16 + lrow;
  const int ar1 = ar0 + 64;
  int br0 = n0 + ar0; br0 = br0 < N ? br0 : N - 1;
  int br1 = n0 + ar1; br1 = br1 < N ? br1 : N - 1;
  const unsigned short* Aptr0 = A + (size_t)(m0 + ar0) * lda + ((lcol ^ (ar0 & 3)) << 3);
  const unsigned short* Aptr1 = A + (size_t)(m0 + ar1) * lda + ((lcol ^ (ar1 & 3)) << 3);
  const unsigned short* Bptr0 = Bt + (size_t)br0 * ldb + ((lcol ^ (ar0 & 3)) << 3);
  const unsigned short* Bptr1 = Bt + (size_t)br1 * ldb + ((lcol ^ (ar1 & 3)) << 3);
  unsigned short* lA0 = &As[wave * 16][0];
  unsigned short* lA1 = &As[64 + wave * 16][0];
  unsigned short* lB0 = &Bs[wave * 16][0];
  unsigned short* lB1 = &Bs[64 + wave * 16][0];
  const int frow = lane & 15, fkb = lane >> 4;
  f32x4 acc[4][4];
#pragma unroll
  for (int i = 0; i < 4; i++)
#pragma unroll
    for (int j = 0; j < 4; j++) acc[i][j] = (f32x4){0.f, 0.f, 0.f, 0.f};

  for (int k0 = 0; k0 < K; k0 += 32) {
    gload16(Aptr0 + k0, lA0);
    gload16(Aptr1 + k0, lA1);
    gload16(Bptr0 + k0, lB0);
    gload16(Bptr1 + k0, lB1);
    __syncthreads();
    short8 af[4], bfr[4];
#pragma unroll
    for (int i = 0; i < 4; i++) {
      int ra = wm + i * 16 + frow;
      af[i] = *(const short8*)&As[ra][(fkb ^ (ra & 3)) << 3];
      int rb = wn + i * 16 + frow;
      bfr[i] = *(const short8*)&Bs[rb][(fkb ^ (rb & 3)) << 3];
    }
#pragma unroll
    for (int i = 0; i < 4; i++)
#pragma unroll
      for (int j = 0; j < 4; j++)
        acc[i][j] = __builtin_amdgcn_mfma_f32_16x16x32_bf16(af[i], bfr[j], acc[i][j], 0, 0, 0);
    __syncthreads();
  }
  const int crow = (lane >> 4) << 2, ccol = lane & 15;
#pragma unroll
  for (int i = 0; i < 4; i++) {
    const int gr = m0 + wm + i * 16 + crow;
#pragma unroll
    for (int j = 0; j < 4; j++) {
      const int gc = n0 + wn + j * 16 + ccol;
      if (gc < N) {
#pragma unroll
        for (int r = 0; r < 4; r++) C[(size_t)(gr + r) * N + gc] = acc[i][j][r];
      }
    }
  }
}

// ---------- fused MLP1: mid = bf16(silu(A*B1t^T) * (A*B2t^T)), N=8192, K=2048 ----------
// B1t = wmlp1T rows [0,8192) (gate), B2t = rows [8192,16384) (up). Saves the
// 64MB mlp1f round-trip + the swiglu kernel (~208MB HBM).
__global__ void __launch_bounds__(256) gemm_dual_swiglu_kernel(const unsigned short* __restrict__ A,
                                                               const unsigned short* __restrict__ Bt,
                                                               unsigned short* __restrict__ mid) {
  __shared__ unsigned short As[128][32];
  __shared__ unsigned short B1s[128][32];
  __shared__ unsigned short B2s[128][32];
  const int tid = threadIdx.x;
  const int m0 = blockIdx.x << 7, n0 = blockIdx.y << 7;
  const int wave = tid >> 6, lane = tid & 63;
  const int wm = (wave >> 1) << 6, wn = (wave & 1) << 6;
  const int lrow = lane >> 2, lcol = lane & 3;
  const int ar0 = wave * 16 + lrow;
  const int ar1 = ar0 + 64;
  const unsigned short* Aptr0 = A + (size_t)(m0 + ar0) * 2048 + ((lcol ^ (ar0 & 3)) << 3);
  const unsigned short* Aptr1 = A + (size_t)(m0 + ar1) * 2048 + ((lcol ^ (ar1 & 3)) << 3);
  const unsigned short* B1p0 = Bt + (size_t)(n0 + ar0) * 2048 + ((lcol ^ (ar0 & 3)) << 3);
  const unsigned short* B1p1 = Bt + (size_t)(n0 + ar1) * 2048 + ((lcol ^ (ar1 & 3)) << 3);
  const unsigned short* B2p0 = B1p0 + (size_t)8192 * 2048;
  const unsigned short* B2p1 = B1p1 + (size_t)8192 * 2048;
  unsigned short* lA0 = &As[wave * 16][0];
  unsigned short* lA1 = &As[64 + wave * 16][0];
  unsigned short* lB10 = &B1s[wave * 16][0];
  unsigned short* lB11 = &B1s[64 + wave * 16][0];
  unsigned short* lB20 = &B2s[wave * 16][0];
  unsigned short* lB21 = &B2s[64 + wave * 16][0];
  const int frow = lane & 15, fkb = lane >> 4;
  f32x4 acc1[4][4], acc2[4][4];
#pragma unroll
  for (int i = 0; i < 4; i++)
#pragma unroll
    for (int j = 0; j < 4; j++) {
      acc1[i][j] = (f32x4){0.f, 0.f, 0.f, 0.f};
      acc2[i][j] = (f32x4){0.f, 0.f, 0.f, 0.f};
    }
  for (int k0 = 0; k0 < 2048; k0 += 32) {
    gload16(Aptr0 + k0, lA0);
    gload16(Aptr1 + k0, lA1);
    gload16(B1p0 + k0, lB10);
    gload16(B1p1 + k0, lB11);
    gload16(B2p0 + k0, lB20);
    gload16(B2p1 + k0, lB21);
    __syncthreads();
    short8 af[4], b1f[4], b2f[4];
#pragma unroll
    for (int i = 0; i < 4; i++) {
      int ra = wm + i * 16 + frow;
      af[i] = *(const short8*)&As[ra][(fkb ^ (ra & 3)) << 3];
      int rb = wn + i * 16 + frow;
      b1f[i] = *(const short8*)&B1s[rb][(fkb ^ (rb & 3)) << 3];
      b2f[i] = *(const short8*)&B2s[rb][(fkb ^ (rb & 3)) << 3];
    }
#pragma unroll
    for (int i = 0; i < 4; i++)
#pragma unroll
      for (int j = 0; j < 4; j++) {
        acc1[i][j] = __builtin_amdgcn_mfma_f32_16x16x32_bf16(af[i], b1f[j], acc1[i][j], 0, 0, 0);
        acc2[i][j] = __builtin_amdgcn_mfma_f32_16x16x32_bf16(af[i], b2f[j], acc2[i][j], 0, 0, 0);
      }
    __syncthreads();
  }
  const int crow = (lane >> 4) << 2, ccol = lane & 15;
#pragma unroll
  for (int i = 0; i < 4; i++) {
    const int gr = m0 + wm + i * 16 + crow;
#pragma unroll
    for (int j = 0; j < 4; j++) {
      const int gc = n0 + wn + j * 16 + ccol;
#pragma unroll
      for (int r = 0; r < 4; r++)
        mid[(size_t)(gr + r) * 8192 + gc] = f2bf(silu_f(acc1[i][j][r]) * acc2[i][j][r]);
    }
  }
}

// ---------- causal dwconv(K=4) + silu + per-head l2norm + qk dot ----------
__global__ void __launch_bounds__(256) conv_kernel(const float* __restrict__ proj,
                                                   const float* __restrict__ cq,
                                                   const float* __restrict__ ck,
                                                   const float* __restrict__ cv,
                                                   float* __restrict__ q, float* __restrict__ k,
                                                   float* __restrict__ v,
                                                   float* __restrict__ qkbuf) {
  const int t = blockIdx.x, tid = threadIdx.x;
  const int c = tid << 3;
  float aq[8] = {0,0,0,0,0,0,0,0}, ak[8] = {0,0,0,0,0,0,0,0}, av[8] = {0,0,0,0,0,0,0,0};
#pragma unroll
  for (int i = 0; i < 4; i++) {
    const int tt = t + i - 3;
    if (tt < 0) continue;
    const float* pr = proj + (size_t)tt * 6144;
    float pq[8], pk[8], pv[8], w0[8], w1[8], w2[8];
    *(float4*)&pq[0] = *(const float4*)(pr + c);        *(float4*)&pq[4] = *(const float4*)(pr + c + 4);
    *(float4*)&pk[0] = *(const float4*)(pr + 2048 + c); *(float4*)&pk[4] = *(const float4*)(pr + 2048 + c + 4);
    *(float4*)&pv[0] = *(const float4*)(pr + 4096 + c); *(float4*)&pv[4] = *(const float4*)(pr + 4096 + c + 4);
    *(float4*)&w0[0] = *(const float4*)(cq + i * 2048 + c); *(float4*)&w0[4] = *(const float4*)(cq + i * 2048 + c + 4);
    *(float4*)&w1[0] = *(const float4*)(ck + i * 2048 + c); *(float4*)&w1[4] = *(const float4*)(ck + i * 2048 + c + 4);
    *(float4*)&w2[0] = *(const float4*)(cv + i * 2048 + c); *(float4*)&w2[4] = *(const float4*)(cv + i * 2048 + c + 4);
#pragma unroll
    for (int j = 0; j < 8; j++) { aq[j] += w0[j]*pq[j]; ak[j] += w1[j]*pk[j]; av[j] += w2[j]*pv[j]; }
  }
  float sq[8], sk[8], sv[8]; float ssq = 0.f, ssk = 0.f;
#pragma unroll
  for (int j = 0; j < 8; j++) {
    sq[j] = silu_f(aq[j]); ssq += sq[j]*sq[j];
    sk[j] = silu_f(ak[j]); ssk += sk[j]*sk[j];
    sv[j] = silu_f(av[j]);
  }
  ssq = red16(ssq); ssk = red16(ssk);
  const float rq = rsqrtf(ssq + 1e-6f) * 0.08838834764831845f;  // * DK^-0.5
  const float rk = rsqrtf(ssk + 1e-6f);
  float oq[8], ok[8]; float qkl = 0.f;
#pragma unroll
  for (int j = 0; j < 8; j++) { oq[j] = sq[j]*rq; ok[j] = sk[j]*rk; qkl += oq[j]*ok[j]; }
  qkl = red16(qkl);
  if ((tid & 15) == 0) qkbuf[(size_t)t * 16 + (tid >> 4)] = qkl;
  float* qo = q + (size_t)t * 2048 + c;
  *(float4*)qo = *(float4*)&oq[0]; *(float4*)(qo + 4) = *(float4*)&oq[4];
  float* ko = k + (size_t)t * 2048 + c;
  *(float4*)ko = *(float4*)&ok[0]; *(float4*)(ko + 4) = *(float4*)&ok[4];
  float* vo = v + (size_t)t * 2048 + c;
  *(float4*)vo = *(float4*)&sv[0]; *(float4*)(vo + 4) = *(float4*)&sv[4];
}

// ---------- packed gates: g4[t][h] = (eg, beta, qk, 0); gab->bf16 ----------
__global__ void __launch_bounds__(64) gates_kernel(const float* __restrict__ small,
                                                   const float* __restrict__ wfb,
                                                   const float* __restrict__ a_log,
                                                   const float* __restrict__ dtb,
                                                   const float* __restrict__ qkbuf,
                                                   float4* __restrict__ g4,
                                                   unsigned short* __restrict__ gab) {
  const int t = blockIdx.x, tid = threadIdx.x;
  const float* srow = small + (size_t)t * 272;
  if (tid < 16) {
    float d = dtb[tid];
    for (int j = 0; j < 128; j++) d += srow[j] * wfb[j * 16 + tid];
    float sp = (d > 20.f) ? d : log1pf(expf(d));
    float eg = expf(-expf(a_log[tid]) * sp);
    float b = srow[128 + tid];
    float bt = 1.f / (1.f + expf(-b));
    g4[t * 16 + tid] = make_float4(eg, bt, qkbuf[t * 16 + tid], 0.f);
  }
  for (int j = tid; j < 128; j += 64) gab[(size_t)t * 128 + j] = f2bf(srow[144 + j]);
}

// ---------- gated delta-rule scan (round-3 known-good version) ----------
// one wave = 4 v-columns of one head; 8 named prefetch slots; DPP reductions.
struct Slot { float4 k0, k1, q0, q1; float eg, qk, btv, bteg; };

__device__ __forceinline__ void load_slot(Slot& X, const float* kb, const float* qb,
                                          const float* vb, const float4* g4b, int tt) {
  const float* kp = kb + (size_t)tt * 2048;
  const float* qp = qb + (size_t)tt * 2048;
  X.k0 = *(const float4*)kp; X.k1 = *(const float4*)(kp + 4);
  X.q0 = *(const float4*)qp; X.q1 = *(const float4*)(qp + 4);
  float4 g = g4b[(size_t)tt * 16];
  float v = vb[(size_t)tt * 2048];
  X.eg = g.x; X.qk = g.z;
  X.btv = g.y * v;            // off-chain precompute
  X.bteg = g.y * g.x;
}

__device__ __forceinline__ void step_slot(const Slot& X, float (&S)[8], float* ob,
                                          bool dostore, int tt) {
  float a0 = fmaf(X.k1.x, S[4], X.k0.x * S[0]);
  float a1 = fmaf(X.k1.y, S[5], X.k0.y * S[1]);
  float a2 = fmaf(X.k1.z, S[6], X.k0.z * S[2]);
  float a3 = fmaf(X.k1.w, S[7], X.k0.w * S[3]);
  float b0 = fmaf(X.q1.x, S[4], X.q0.x * S[0]);
  float b1 = fmaf(X.q1.y, S[5], X.q0.y * S[1]);
  float b2 = fmaf(X.q1.z, S[6], X.q0.z * S[2]);
  float b3 = fmaf(X.q1.w, S[7], X.q0.w * S[3]);
  float kS = red16d((a0 + a1) + (a2 + a3));
  float qS = red16d((b0 + b1) + (b2 + b3));
  float delta = fmaf(-X.bteg, kS, X.btv);   // bt*(v - eg*kS)
  S[0] = fmaf(X.k0.x, delta, X.eg * S[0]);
  S[1] = fmaf(X.k0.y, delta, X.eg * S[1]);
  S[2] = fmaf(X.k0.z, delta, X.eg * S[2]);
  S[3] = fmaf(X.k0.w, delta, X.eg * S[3]);
  S[4] = fmaf(X.k1.x, delta, X.eg * S[4]);
  S[5] = fmaf(X.k1.y, delta, X.eg * S[5]);
  S[6] = fmaf(X.k1.z, delta, X.eg * S[6]);
  S[7] = fmaf(X.k1.w, delta, X.eg * S[7]);
  if (dostore) ob[(size_t)tt * 2048] = fmaf(X.qk, delta, X.eg * qS);
}

__global__ void __launch_bounds__(64, 1) scan_kernel(const float* __restrict__ q,
                                                     const float* __restrict__ k,
                                                     const float* __restrict__ v,
                                                     const float4* __restrict__ g4,
                                                     float* __restrict__ o) {
  // XCD swizzle: b&7 = XCD -> heads 2x,2x+1 stay on one XCD
  const int b = blockIdx.x;            // 512 = 16 heads * 32 slices
  const int xcd = b & 7, r = b >> 3;
  const int h = (xcd << 1) | (r >> 5);
  const int vbase = (r & 31) << 2;
  const int lane = threadIdx.x;
  const int kl = lane & 15, vl = lane >> 4;
  const int vcol = vbase + vl;
  const int koff = h * 128 + kl * 8;
  const int voff = h * 128 + vcol;
  const float* kb = k + koff;
  const float* qb = q + koff;
  const float* vb = v + voff;
  const float4* g4b = g4 + h;
  float* ob = o + voff;
  const bool dostore = (kl == 0);
  float S[8] = {0,0,0,0,0,0,0,0};
  Slot s0, s1, s2, s3, s4, s5, s6, s7;
  load_slot(s0, kb, qb, vb, g4b, 0);
  load_slot(s1, kb, qb, vb, g4b, 1);
  load_slot(s2, kb, qb, vb, g4b, 2);
  load_slot(s3, kb, qb, vb, g4b, 3);
  load_slot(s4, kb, qb, vb, g4b, 4);
  load_slot(s5, kb, qb, vb, g4b, 5);
  load_slot(s6, kb, qb, vb, g4b, 6);
  load_slot(s7, kb, qb, vb, g4b, 7);
  // NOTE: prefetch reads past t=1023 land in adjacent ws regions (in-bounds,
  // never consumed) -- no clamp on the critical path.
  for (int t = 0; t < 1024; t += 8) {
    step_slot(s0, S, ob, dostore, t + 0); load_slot(s0, kb, qb, vb, g4b, t + 8);
    step_slot(s1, S, ob, dostore, t + 1); load_slot(s1, kb, qb, vb, g4b, t + 9);
    step_slot(s2, S, ob, dostore, t + 2); load_slot(s2, kb, qb, vb, g4b, t + 10);
    step_slot(s3, S, ob, dostore, t + 3); load_slot(s3, kb, qb, vb, g4b, t + 11);
    step_slot(s4, S, ob, dostore, t + 4); load_slot(s4, kb, qb, vb, g4b, t + 12);
    step_slot(s5, S, ob, dostore, t + 5); load_slot(s5, kb, qb, vb, g4b, t + 13);
    step_slot(s6, S, ob, dostore, t + 6); load_slot(s6, kb, qb, vb, g4b, t + 14);
    step_slot(s7, S, ob, dostore, t + 7); load_slot(s7, kb, qb, vb, g4b, t + 15);
  }
}

// ---------- o_gated = bf16(rmsnorm_head(o)*w * silu(gate)) ----------
__global__ void __launch_bounds__(256) gate_o_kernel(const float* __restrict__ o,
                                                     const float* __restrict__ gate,
                                                     const float* __restrict__ onw,
                                                     unsigned short* __restrict__ ogb) {
  const int t = blockIdx.x, tid = threadIdx.x;
  const int c = tid << 3;
  const float* orow = o + (size_t)t * 2048 + c;
  float ov[8]; *(float4*)&ov[0] = *(const float4*)orow; *(float4*)&ov[4] = *(const float4*)(orow + 4);
  float ss = 0.f;
#pragma unroll
  for (int j = 0; j < 8; j++) ss += ov[j] * ov[j];
  ss = red16(ss);
  const float rn = rsqrtf(ss * (1.f / 128.f) + 1e-6f);
  const int dv = (tid & 15) << 3;
  float wv[8]; *(float4*)&wv[0] = *(const float4*)(onw + dv); *(float4*)&wv[4] = *(const float4*)(onw + dv + 4);
  const float* grow = gate + (size_t)t * 2048 + c;
  float gv[8]; *(float4*)&gv[0] = *(const float4*)grow; *(float4*)&gv[4] = *(const float4*)(grow + 4);
  u16x8 r;
#pragma unroll
  for (int j = 0; j < 8; j++) r[j] = f2bf(ov[j] * rn * wv[j] * silu_f(gv[j]));
  *(u16x8*)(ogb + (size_t)t * 2048 + c) = r;
}

// ---------- out = a + b + c ----------
__global__ void final_add3_kernel(const float* __restrict__ a, const float* __restrict__ b,
                                  const float* __restrict__ c, float* __restrict__ out) {
  const int NU = 1024 * 512;
  for (int u = blockIdx.x * blockDim.x + threadIdx.x; u < NU; u += gridDim.x * blockDim.x) {
    float4 va = ((const float4*)a)[u];
    float4 vb = ((const float4*)b)[u];
    float4 vc = ((const float4*)c)[u];
    va.x += vb.x + vc.x; va.y += vb.y + vc.y; va.z += vb.z + vc.z; va.w += vb.w + vc.w;
    ((float4*)out)[u] = va;
  }
}

// ---------- ws layout (bytes) ----------
constexpr size_t SZ_WQKVT   = (size_t)6144 * 2048 * 2;
constexpr size_t SZ_WSMALLT = (size_t)272 * 2048 * 2;
constexpr size_t SZ_WGBT    = (size_t)2048 * 128 * 2;
constexpr size_t SZ_WOT     = (size_t)2048 * 2048 * 2;
constexpr size_t SZ_WMLP1T  = (size_t)16384 * 2048 * 2;
constexpr size_t SZ_WDOWNT  = (size_t)2048 * 8192 * 2;
constexpr size_t OFF_WQKVT   = 0;
constexpr size_t OFF_WSMALLT = OFF_WQKVT + SZ_WQKVT;
constexpr size_t OFF_WGBT    = OFF_WSMALLT + SZ_WSMALLT;
constexpr size_t OFF_WOT     = OFF_WGBT + SZ_WGBT;
constexpr size_t OFF_WMLP1T  = OFF_WOT + SZ_WOT;
constexpr size_t OFF_WDOWNT  = OFF_WMLP1T + SZ_WMLP1T;
constexpr size_t A0          = OFF_WDOWNT + SZ_WDOWNT;
constexpr size_t OFF_HB    = A0;
constexpr size_t OFF_PROJ  = OFF_HB + (size_t)1024 * 2048 * 2;
constexpr size_t OFF_SMALL = OFF_PROJ + (size_t)1024 * 6144 * 4;
constexpr size_t OFF_Q     = OFF_SMALL + (size_t)1024 * 272 * 4;
constexpr size_t OFF_K     = OFF_Q + (size_t)1024 * 2048 * 4;
constexpr size_t OFF_V     = OFF_K + (size_t)1024 * 2048 * 4;
constexpr size_t OFF_G     = OFF_V + (size_t)1024 * 2048 * 4;   // scan over-read pad
constexpr size_t OFF_BETA  = OFF_G + (size_t)1024 * 16 * 4;
constexpr size_t OFF_GAB   = OFF_BETA + (size_t)1024 * 16 * 4;
constexpr size_t OFF_GATE  = OFF_GAB + (size_t)1024 * 128 * 2;
constexpr size_t OFF_O     = OFF_GATE + (size_t)1024 * 2048 * 4;
constexpr size_t OFF_OGB   = OFF_O + (size_t)1024 * 2048 * 4;
constexpr size_t OFF_OPROJ = OFF_OGB + (size_t)1024 * 2048 * 2;
constexpr size_t OFF_X1    = OFF_OPROJ + (size_t)1024 * 2048 * 4;
constexpr size_t OFF_H2B   = OFF_X1 + (size_t)1024 * 2048 * 4;
constexpr size_t OFF_MID    = A0 + (size_t)1024 * 16384 * 4;   // keep r6 placement
constexpr size_t OFF_MLPOUT = OFF_H2B + (size_t)1024 * 2048 * 2;
constexpr size_t OFF_QKB    = OFF_MLPOUT + (size_t)1024 * 2048 * 4;     // [1024][16] f32
constexpr size_t OFF_G4     = OFF_QKB + (size_t)1024 * 16 * 4;          // [1040][16] float4 (pad for tail prefetch)
constexpr size_t OFF_MLPOUT2= OFF_G4 + (size_t)1040 * 16 * 16;
constexpr size_t WS_NEED    = OFF_MLPOUT2 + (size_t)1024 * 2048 * 4;
constexpr size_t OFF_OPROJ2 = OFF_O;   // liveness alias

extern "C" void kernel_launch(void* const* d_in, const int* in_sizes, int n_in,
                              void* d_out, int out_size, void* d_ws, size_t ws_size,
                              hipStream_t stream) {
  (void)in_sizes; (void)n_in; (void)out_size;
  const float* x     = (const float*)d_in[0];
  const float* wq    = (const float*)d_in[1];
  const float* wk    = (const float*)d_in[2];
  const float* wv    = (const float*)d_in[3];
  const float* cq    = (const float*)d_in[4];
  const float* ck    = (const float*)d_in[5];
  const float* cv    = (const float*)d_in[6];
  const float* wfa   = (const float*)d_in[7];
  const float* wfb   = (const float*)d_in[8];
  const float* wb    = (const float*)d_in[9];
  const float* wga   = (const float*)d_in[10];
  const float* wgb   = (const float*)d_in[11];
  const float* a_log = (const float*)d_in[12];
  const float* dtb   = (const float*)d_in[13];
  const float* onw   = (const float*)d_in[14];
  const float* wo    = (const float*)d_in[15];
  const float* ln1   = (const float*)d_in[16];
  const float* ln2   = (const float*)d_in[17];
  const float* wgate = (const float*)d_in[18];
  const float* wup   = (const float*)d_in[19];
  const float* wdown = (const float*)d_in[20];
  float* out = (float*)d_out;
  char* ws = (char*)d_ws;
  if (ws_size < WS_NEED) return;

  unsigned short* wqkvT   = (unsigned short*)(ws + OFF_WQKVT);
  unsigned short* wsmallT = (unsigned short*)(ws + OFF_WSMALLT);
  unsigned short* wgbT    = (unsigned short*)(ws + OFF_WGBT);
  unsigned short* woT     = (unsigned short*)(ws + OFF_WOT);
  unsigned short* wmlp1T  = (unsigned short*)(ws + OFF_WMLP1T);
  unsigned short* wdownT  = (unsigned short*)(ws + OFF_WDOWNT);
  unsigned short* hb      = (unsigned short*)(ws + OFF_HB);
  float* projf  = (float*)(ws + OFF_PROJ);
  float* smallf = (float*)(ws + OFF_SMALL);
  float* qf     = (float*)(ws + OFF_Q);
  float* kf     = (float*)(ws + OFF_K);
  float* vf     = (float*)(ws + OFF_V);
  unsigned short* gab = (unsigned short*)(ws + OFF_GAB);
  float* gatef  = (float*)(ws + OFF_GATE);
  float* of     = (float*)(ws + OFF_O);
  unsigned short* ogb = (unsigned short*)(ws + OFF_OGB);
  float* oprojf = (float*)(ws + OFF_OPROJ);
  float* oproj2f= (float*)(ws + OFF_OPROJ2);
  float* x1f    = (float*)(ws + OFF_X1);
  unsigned short* h2b = (unsigned short*)(ws + OFF_H2B);
  unsigned short* midb = (unsigned short*)(ws + OFF_MID);
  float* mlpoutf = (float*)(ws + OFF_MLPOUT);
  float* mlpout2f = (float*)(ws + OFF_MLPOUT2);
  float* qkbuf  = (float*)(ws + OFF_QKB);
  float4* g4    = (float4*)(ws + OFF_G4);

  trans_kernel<<<dim3(64, 64), 256, 0, stream>>>(wq, wqkvT, 2048, 2048);
  trans_kernel<<<dim3(64, 64), 256, 0, stream>>>(wk, wqkvT + (size_t)2048 * 2048, 2048, 2048);
  trans_kernel<<<dim3(64, 64), 256, 0, stream>>>(wv, wqkvT + (size_t)4096 * 2048, 2048, 2048);
  trans_kernel<<<dim3(4, 64), 256, 0, stream>>>(wfa, wsmallT, 2048, 128);
  trans_kernel<<<dim3(1, 64), 256, 0, stream>>>(wb, wsmallT + (size_t)128 * 2048, 2048, 16);
  trans_kernel<<<dim3(4, 64), 256, 0, stream>>>(wga, wsmallT + (size_t)144 * 2048, 2048, 128);
  trans_kernel<<<dim3(64, 4), 256, 0, stream>>>(wgb, wgbT, 128, 2048);
  trans_kernel<<<dim3(64, 64), 256, 0, stream>>>(wo, woT, 2048, 2048);
  trans_kernel<<<dim3(256, 64), 256, 0, stream>>>(wgate, wmlp1T, 2048, 8192);
  trans_kernel<<<dim3(256, 64), 256, 0, stream>>>(wup, wmlp1T + (size_t)8192 * 2048, 2048, 8192);
  trans_kernel<<<dim3(64, 256), 256, 0, stream>>>(wdown, wdownT, 8192, 2048);

  rmsnorm_bf16_kernel<<<1024, 256, 0, stream>>>(x, ln1, hb);
  gemm_bt_kernel<<<dim3(8, 48), 256, 0, stream>>>(hb, wqkvT, projf, 1024, 6144, 2048, 2048, 2048);
  gemm_bt_kernel<<<dim3(8, 3), 256, 0, stream>>>(hb, wsmallT, smallf, 1024, 272, 2048, 2048, 2048);
  conv_kernel<<<1024, 256, 0, stream>>>(projf, cq, ck, cv, qf, kf, vf, qkbuf);
  gates_kernel<<<1024, 64, 0, stream>>>(smallf, wfb, a_log, dtb, qkbuf, g4, gab);
  gemm_bt_kernel<<<dim3(8, 16), 256, 0, stream>>>(gab, wgbT, gatef, 1024, 2048, 128, 128, 128);
  scan_kernel<<<512, 64, 0, stream>>>(qf, kf, vf, g4, of);
  gate_o_kernel<<<1024, 256, 0, stream>>>(of, gatef, onw, ogb);
  gemm_bt_kernel<<<dim3(8, 16), 256, 0, stream>>>(ogb, woT, oprojf, 1024, 2048, 1024, 2048, 2048);
  gemm_bt_kernel<<<dim3(8, 16), 256, 0, stream>>>(ogb + 1024, woT + 1024, oproj2f, 1024, 2048, 1024, 2048, 2048);
  add3_rmsnorm_kernel<<<1024, 256, 0, stream>>>(x, oprojf, oproj2f, ln2, x1f, h2b);
  gemm_dual_swiglu_kernel<<<dim3(8, 64), 256, 0, stream>>>(h2b, wmlp1T, midb);
  gemm_bt_kernel<<<dim3(8, 16), 256, 0, stream>>>(midb, wdownT, mlpoutf, 1024, 2048, 4096, 8192, 8192);
  gemm_bt_kernel<<<dim3(8, 16), 256, 0, stream>>>(midb + 4096, wdownT + 4096, mlpout2f, 1024, 2048, 4096, 8192, 8192);
  final_add3_kernel<<<2048, 256, 0, stream>>>(x1f, mlpoutf, mlpout2f, out);
}

// Round 9
// 902.339 us; speedup vs baseline: 1.0638x; 1.0255x over previous
//
#include <hip/hip_runtime.h>
#include <hip/hip_bf16.h>

typedef __attribute__((ext_vector_type(8))) short short8;
typedef __attribute__((ext_vector_type(4))) float f32x4;
typedef __attribute__((ext_vector_type(8))) unsigned short u16x8;
typedef __attribute__((ext_vector_type(4))) unsigned short u16x4;

// ---------- helpers ----------
__device__ __forceinline__ unsigned short f2bf(float f) {
  unsigned u = __float_as_uint(f);
  u += 0x7fffu + ((u >> 16) & 1u);          // round-to-nearest-even
  return (unsigned short)(u >> 16);
}
__device__ __forceinline__ float silu_f(float x) { return x / (1.f + __expf(-x)); }
__device__ __forceinline__ float red16(float v) {
  v += __shfl_xor(v, 1); v += __shfl_xor(v, 2);
  v += __shfl_xor(v, 4); v += __shfl_xor(v, 8);
  return v;
}
template <int CTRL>
__device__ __forceinline__ float dpp_mv(float v) {
  return __int_as_float(__builtin_amdgcn_update_dpp(0, __float_as_int(v), CTRL, 0xF, 0xF, true));
}
__device__ __forceinline__ float red16d(float v) {
  v += dpp_mv<0xB1>(v);   // quad_perm [1,0,3,2]
  v += dpp_mv<0x4E>(v);   // quad_perm [2,3,0,1]
  v += dpp_mv<0x141>(v);  // row_half_mirror
  v += dpp_mv<0x140>(v);  // row_mirror
  return v;
}
__device__ __forceinline__ void gload16(const void* g, void* l) {
  __builtin_amdgcn_global_load_lds((const __attribute__((address_space(1))) void*)g,
                                   (__attribute__((address_space(3))) void*)l, 16, 0, 0);
}

// ---------- transpose fp32 [R][C] -> bf16 [C][R] ----------
__global__ void __launch_bounds__(256) trans_kernel(const float* __restrict__ src,
                                                    unsigned short* __restrict__ dst,
                                                    int R, int C) {
  __shared__ float tile[32][33];
  const int tx = threadIdx.x & 31, ty = threadIdx.x >> 5;
  const int c = blockIdx.x * 32 + tx;
#pragma unroll
  for (int i = 0; i < 32; i += 8) {
    int r = blockIdx.y * 32 + ty + i;
    if (r < R && c < C) tile[ty + i][tx] = src[(size_t)r * C + c];
  }
  __syncthreads();
  const int rc = blockIdx.y * 32 + tx;
#pragma unroll
  for (int i = 0; i < 32; i += 8) {
    int cc = blockIdx.x * 32 + ty + i;
    if (cc < C && rc < R) dst[(size_t)cc * R + rc] = f2bf(tile[tx][ty + i]);
  }
}

// ---------- rmsnorm (D=2048) -> bf16 ----------
__global__ void __launch_bounds__(256) rmsnorm_bf16_kernel(const float* __restrict__ x,
                                                           const float* __restrict__ w,
                                                           unsigned short* __restrict__ outb) {
  const int t = blockIdx.x, tid = threadIdx.x;
  const float* xr = x + (size_t)t * 2048 + tid * 8;
  float4 v0 = *(const float4*)xr, v1 = *(const float4*)(xr + 4);
  float ss = v0.x*v0.x + v0.y*v0.y + v0.z*v0.z + v0.w*v0.w
           + v1.x*v1.x + v1.y*v1.y + v1.z*v1.z + v1.w*v1.w;
#pragma unroll
  for (int m = 1; m < 64; m <<= 1) ss += __shfl_xor(ss, m);
  __shared__ float sb[4];
  if ((tid & 63) == 0) sb[tid >> 6] = ss;
  __syncthreads();
  float rn = rsqrtf((sb[0] + sb[1] + sb[2] + sb[3]) * (1.f / 2048.f) + 1e-6f);
  const float* wr = w + tid * 8;
  float4 w0 = *(const float4*)wr, w1 = *(const float4*)(wr + 4);
  u16x8 r;
  r[0]=f2bf(v0.x*rn*w0.x); r[1]=f2bf(v0.y*rn*w0.y); r[2]=f2bf(v0.z*rn*w0.z); r[3]=f2bf(v0.w*rn*w0.w);
  r[4]=f2bf(v1.x*rn*w1.x); r[5]=f2bf(v1.y*rn*w1.y); r[6]=f2bf(v1.z*rn*w1.z); r[7]=f2bf(v1.w*rn*w1.w);
  *(u16x8*)(outb + (size_t)t * 2048 + tid * 8) = r;
}

// ---------- x1 = x + y1 + y2 ; h2b = bf16(rmsnorm(x1)*w) ----------
__global__ void __launch_bounds__(256) add3_rmsnorm_kernel(const float* __restrict__ x,
                                                           const float* __restrict__ y1,
                                                           const float* __restrict__ y2,
                                                           const float* __restrict__ w,
                                                           float* __restrict__ x1,
                                                           unsigned short* __restrict__ h2b) {
  const int t = blockIdx.x, tid = threadIdx.x;
  const int c = tid * 8;
  const float* xr = x + (size_t)t * 2048 + c;
  const float* yr = y1 + (size_t)t * 2048 + c;
  const float* zr = y2 + (size_t)t * 2048 + c;
  float s[8]; float ss = 0.f;
  float4 a0 = *(const float4*)xr, a1 = *(const float4*)(xr + 4);
  float4 b0 = *(const float4*)yr, b1 = *(const float4*)(yr + 4);
  float4 c0 = *(const float4*)zr, c1 = *(const float4*)(zr + 4);
  s[0]=a0.x+b0.x+c0.x; s[1]=a0.y+b0.y+c0.y; s[2]=a0.z+b0.z+c0.z; s[3]=a0.w+b0.w+c0.w;
  s[4]=a1.x+b1.x+c1.x; s[5]=a1.y+b1.y+c1.y; s[6]=a1.z+b1.z+c1.z; s[7]=a1.w+b1.w+c1.w;
#pragma unroll
  for (int j = 0; j < 8; j++) ss += s[j] * s[j];
#pragma unroll
  for (int m = 1; m < 64; m <<= 1) ss += __shfl_xor(ss, m);
  __shared__ float sb[4];
  if ((tid & 63) == 0) sb[tid >> 6] = ss;
  __syncthreads();
  float rn = rsqrtf((sb[0] + sb[1] + sb[2] + sb[3]) * (1.f / 2048.f) + 1e-6f);
  float* xo = x1 + (size_t)t * 2048 + c;
  *(float4*)xo = *(float4*)&s[0];
  *(float4*)(xo + 4) = *(float4*)&s[4];
  const float* wr = w + c;
  float4 w0 = *(const float4*)wr, w1 = *(const float4*)(wr + 4);
  float wv[8] = {w0.x,w0.y,w0.z,w0.w,w1.x,w1.y,w1.z,w1.w};
  u16x8 r;
#pragma unroll
  for (int j = 0; j < 8; j++) r[j] = f2bf(s[j] * rn * wv[j]);
  *(u16x8*)(h2b + (size_t)t * 2048 + c) = r;
}

// ---------- bf16 GEMM: C[M,N] = A[M,K] * Bt[N,K]^T  (m97-style, strided) ----------
__global__ void __launch_bounds__(256) gemm_bt_kernel(const unsigned short* __restrict__ A,
                                                      const unsigned short* __restrict__ Bt,
                                                      float* __restrict__ C,
                                                      int M, int N, int K, int lda, int ldb) {
  __shared__ unsigned short As[128][32];
  __shared__ unsigned short Bs[128][32];
  const int tid = threadIdx.x;
  const int m0 = blockIdx.x << 7, n0 = blockIdx.y << 7;
  const int wave = tid >> 6, lane = tid & 63;
  const int wm = (wave >> 1) << 6, wn = (wave & 1) << 6;
  const int lrow = lane >> 2, lcol = lane & 3;
  const int ar0 = wave * 16 + lrow;
  const int ar1 = ar0 + 64;
  int br0 = n0 + ar0; br0 = br0 < N ? br0 : N - 1;
  int br1 = n0 + ar1; br1 = br1 < N ? br1 : N - 1;
  const unsigned short* Aptr0 = A + (size_t)(m0 + ar0) * lda + ((lcol ^ (ar0 & 3)) << 3);
  const unsigned short* Aptr1 = A + (size_t)(m0 + ar1) * lda + ((lcol ^ (ar1 & 3)) << 3);
  const unsigned short* Bptr0 = Bt + (size_t)br0 * ldb + ((lcol ^ (ar0 & 3)) << 3);
  const unsigned short* Bptr1 = Bt + (size_t)br1 * ldb + ((lcol ^ (ar1 & 3)) << 3);
  unsigned short* lA0 = &As[wave * 16][0];
  unsigned short* lA1 = &As[64 + wave * 16][0];
  unsigned short* lB0 = &Bs[wave * 16][0];
  unsigned short* lB1 = &Bs[64 + wave * 16][0];
  const int frow = lane & 15, fkb = lane >> 4;
  f32x4 acc[4][4];
#pragma unroll
  for (int i = 0; i < 4; i++)
#pragma unroll
    for (int j = 0; j < 4; j++) acc[i][j] = (f32x4){0.f, 0.f, 0.f, 0.f};

  for (int k0 = 0; k0 < K; k0 += 32) {
    gload16(Aptr0 + k0, lA0);
    gload16(Aptr1 + k0, lA1);
    gload16(Bptr0 + k0, lB0);
    gload16(Bptr1 + k0, lB1);
    __syncthreads();
    short8 af[4], bfr[4];
#pragma unroll
    for (int i = 0; i < 4; i++) {
      int ra = wm + i * 16 + frow;
      af[i] = *(const short8*)&As[ra][(fkb ^ (ra & 3)) << 3];
      int rb = wn + i * 16 + frow;
      bfr[i] = *(const short8*)&Bs[rb][(fkb ^ (rb & 3)) << 3];
    }
#pragma unroll
    for (int i = 0; i < 4; i++)
#pragma unroll
      for (int j = 0; j < 4; j++)
        acc[i][j] = __builtin_amdgcn_mfma_f32_16x16x32_bf16(af[i], bfr[j], acc[i][j], 0, 0, 0);
    __syncthreads();
  }
  const int crow = (lane >> 4) << 2, ccol = lane & 15;
#pragma unroll
  for (int i = 0; i < 4; i++) {
    const int gr = m0 + wm + i * 16 + crow;
#pragma unroll
    for (int j = 0; j < 4; j++) {
      const int gc = n0 + wn + j * 16 + ccol;
      if (gc < N) {
#pragma unroll
        for (int r = 0; r < 4; r++) C[(size_t)(gr + r) * N + gc] = acc[i][j][r];
      }
    }
  }
}

// ---------- fused MLP1: mid = bf16(silu(A*B1t^T) * (A*B2t^T)), N=8192, K=2048 ----------
__global__ void __launch_bounds__(256) gemm_dual_swiglu_kernel(const unsigned short* __restrict__ A,
                                                               const unsigned short* __restrict__ Bt,
                                                               unsigned short* __restrict__ mid) {
  __shared__ unsigned short As[128][32];
  __shared__ unsigned short B1s[128][32];
  __shared__ unsigned short B2s[128][32];
  const int tid = threadIdx.x;
  const int m0 = blockIdx.x << 7, n0 = blockIdx.y << 7;
  const int wave = tid >> 6, lane = tid & 63;
  const int wm = (wave >> 1) << 6, wn = (wave & 1) << 6;
  const int lrow = lane >> 2, lcol = lane & 3;
  const int ar0 = wave * 16 + lrow;
  const int ar1 = ar0 + 64;
  const unsigned short* Aptr0 = A + (size_t)(m0 + ar0) * 2048 + ((lcol ^ (ar0 & 3)) << 3);
  const unsigned short* Aptr1 = A + (size_t)(m0 + ar1) * 2048 + ((lcol ^ (ar1 & 3)) << 3);
  const unsigned short* B1p0 = Bt + (size_t)(n0 + ar0) * 2048 + ((lcol ^ (ar0 & 3)) << 3);
  const unsigned short* B1p1 = Bt + (size_t)(n0 + ar1) * 2048 + ((lcol ^ (ar1 & 3)) << 3);
  const unsigned short* B2p0 = B1p0 + (size_t)8192 * 2048;
  const unsigned short* B2p1 = B1p1 + (size_t)8192 * 2048;
  unsigned short* lA0 = &As[wave * 16][0];
  unsigned short* lA1 = &As[64 + wave * 16][0];
  unsigned short* lB10 = &B1s[wave * 16][0];
  unsigned short* lB11 = &B1s[64 + wave * 16][0];
  unsigned short* lB20 = &B2s[wave * 16][0];
  unsigned short* lB21 = &B2s[64 + wave * 16][0];
  const int frow = lane & 15, fkb = lane >> 4;
  f32x4 acc1[4][4], acc2[4][4];
#pragma unroll
  for (int i = 0; i < 4; i++)
#pragma unroll
    for (int j = 0; j < 4; j++) {
      acc1[i][j] = (f32x4){0.f, 0.f, 0.f, 0.f};
      acc2[i][j] = (f32x4){0.f, 0.f, 0.f, 0.f};
    }
  for (int k0 = 0; k0 < 2048; k0 += 32) {
    gload16(Aptr0 + k0, lA0);
    gload16(Aptr1 + k0, lA1);
    gload16(B1p0 + k0, lB10);
    gload16(B1p1 + k0, lB11);
    gload16(B2p0 + k0, lB20);
    gload16(B2p1 + k0, lB21);
    __syncthreads();
    short8 af[4], b1f[4], b2f[4];
#pragma unroll
    for (int i = 0; i < 4; i++) {
      int ra = wm + i * 16 + frow;
      af[i] = *(const short8*)&As[ra][(fkb ^ (ra & 3)) << 3];
      int rb = wn + i * 16 + frow;
      b1f[i] = *(const short8*)&B1s[rb][(fkb ^ (rb & 3)) << 3];
      b2f[i] = *(const short8*)&B2s[rb][(fkb ^ (rb & 3)) << 3];
    }
#pragma unroll
    for (int i = 0; i < 4; i++)
#pragma unroll
      for (int j = 0; j < 4; j++) {
        acc1[i][j] = __builtin_amdgcn_mfma_f32_16x16x32_bf16(af[i], b1f[j], acc1[i][j], 0, 0, 0);
        acc2[i][j] = __builtin_amdgcn_mfma_f32_16x16x32_bf16(af[i], b2f[j], acc2[i][j], 0, 0, 0);
      }
    __syncthreads();
  }
  const int crow = (lane >> 4) << 2, ccol = lane & 15;
#pragma unroll
  for (int i = 0; i < 4; i++) {
    const int gr = m0 + wm + i * 16 + crow;
#pragma unroll
    for (int j = 0; j < 4; j++) {
      const int gc = n0 + wn + j * 16 + ccol;
#pragma unroll
      for (int r = 0; r < 4; r++)
        mid[(size_t)(gr + r) * 8192 + gc] = f2bf(silu_f(acc1[i][j][r]) * acc2[i][j][r]);
    }
  }
}

// ---------- causal dwconv(K=4) + silu + per-head l2norm + qk dot ----------
__global__ void __launch_bounds__(256) conv_kernel(const float* __restrict__ proj,
                                                   const float* __restrict__ cq,
                                                   const float* __restrict__ ck,
                                                   const float* __restrict__ cv,
                                                   float* __restrict__ q, float* __restrict__ k,
                                                   float* __restrict__ v,
                                                   float* __restrict__ qkbuf) {
  const int t = blockIdx.x, tid = threadIdx.x;
  const int c = tid << 3;
  float aq[8] = {0,0,0,0,0,0,0,0}, ak[8] = {0,0,0,0,0,0,0,0}, av[8] = {0,0,0,0,0,0,0,0};
#pragma unroll
  for (int i = 0; i < 4; i++) {
    const int tt = t + i - 3;
    if (tt < 0) continue;
    const float* pr = proj + (size_t)tt * 6144;
    float pq[8], pk[8], pv[8], w0[8], w1[8], w2[8];
    *(float4*)&pq[0] = *(const float4*)(pr + c);        *(float4*)&pq[4] = *(const float4*)(pr + c + 4);
    *(float4*)&pk[0] = *(const float4*)(pr + 2048 + c); *(float4*)&pk[4] = *(const float4*)(pr + 2048 + c + 4);
    *(float4*)&pv[0] = *(const float4*)(pr + 4096 + c); *(float4*)&pv[4] = *(const float4*)(pr + 4096 + c + 4);
    *(float4*)&w0[0] = *(const float4*)(cq + i * 2048 + c); *(float4*)&w0[4] = *(const float4*)(cq + i * 2048 + c + 4);
    *(float4*)&w1[0] = *(const float4*)(ck + i * 2048 + c); *(float4*)&w1[4] = *(const float4*)(ck + i * 2048 + c + 4);
    *(float4*)&w2[0] = *(const float4*)(cv + i * 2048 + c); *(float4*)&w2[4] = *(const float4*)(cv + i * 2048 + c + 4);
#pragma unroll
    for (int j = 0; j < 8; j++) { aq[j] += w0[j]*pq[j]; ak[j] += w1[j]*pk[j]; av[j] += w2[j]*pv[j]; }
  }
  float sq[8], sk[8], sv[8]; float ssq = 0.f, ssk = 0.f;
#pragma unroll
  for (int j = 0; j < 8; j++) {
    sq[j] = silu_f(aq[j]); ssq += sq[j]*sq[j];
    sk[j] = silu_f(ak[j]); ssk += sk[j]*sk[j];
    sv[j] = silu_f(av[j]);
  }
  ssq = red16(ssq); ssk = red16(ssk);
  const float rq = rsqrtf(ssq + 1e-6f) * 0.08838834764831845f;  // * DK^-0.5
  const float rk = rsqrtf(ssk + 1e-6f);
  float oq[8], ok[8]; float qkl = 0.f;
#pragma unroll
  for (int j = 0; j < 8; j++) { oq[j] = sq[j]*rq; ok[j] = sk[j]*rk; qkl += oq[j]*ok[j]; }
  qkl = red16(qkl);
  if ((tid & 15) == 0) qkbuf[(size_t)t * 16 + (tid >> 4)] = qkl;
  float* qo = q + (size_t)t * 2048 + c;
  *(float4*)qo = *(float4*)&oq[0]; *(float4*)(qo + 4) = *(float4*)&oq[4];
  float* ko = k + (size_t)t * 2048 + c;
  *(float4*)ko = *(float4*)&ok[0]; *(float4*)(ko + 4) = *(float4*)&ok[4];
  float* vo = v + (size_t)t * 2048 + c;
  *(float4*)vo = *(float4*)&sv[0]; *(float4*)(vo + 4) = *(float4*)&sv[4];
}

// ---------- packed gates: g4[t][h] = (eg, beta, qk, 0); gab->bf16 ----------
__global__ void __launch_bounds__(64) gates_kernel(const float* __restrict__ small,
                                                   const float* __restrict__ wfb,
                                                   const float* __restrict__ a_log,
                                                   const float* __restrict__ dtb,
                                                   const float* __restrict__ qkbuf,
                                                   float4* __restrict__ g4,
                                                   unsigned short* __restrict__ gab) {
  const int t = blockIdx.x, tid = threadIdx.x;
  const float* srow = small + (size_t)t * 272;
  if (tid < 16) {
    float d = dtb[tid];
    for (int j = 0; j < 128; j++) d += srow[j] * wfb[j * 16 + tid];
    float sp = (d > 20.f) ? d : log1pf(expf(d));
    float eg = expf(-expf(a_log[tid]) * sp);
    float b = srow[128 + tid];
    float bt = 1.f / (1.f + expf(-b));
    g4[t * 16 + tid] = make_float4(eg, bt, qkbuf[t * 16 + tid], 0.f);
  }
  for (int j = tid; j < 128; j += 64) gab[(size_t)t * 128 + j] = f2bf(srow[144 + j]);
}

// ---------- gated delta-rule scan v6: intra-chunk asm pipeline ----------
// one wave = 4 v-cols of one head. Per chunk (8 steps): issue ALL 48 loads at
// the TOP of the iteration, then consume with descending counted vmcnt.
// Soundness vs v4/v5 failures: slot registers are written and consumed WITHIN
// one iteration (dead at the backedge) -> no loop-carried PHI copies of
// in-flight asm outputs (that was the corruption mechanism in r6/r7).
struct SlotR { float4 k0, k1, q0, q1, ga; float vv; };

#define ISSUE(SL)                                                            \
  asm volatile("global_load_dwordx4 %0, %6, off\n\t"                         \
               "global_load_dwordx4 %1, %6, off offset:16\n\t"               \
               "global_load_dwordx4 %2, %7, off\n\t"                         \
               "global_load_dwordx4 %3, %7, off offset:16\n\t"               \
               "global_load_dwordx4 %4, %8, off\n\t"                         \
               "global_load_dword %5, %9, off"                               \
               : "=&v"(SL.k0), "=&v"(SL.k1), "=&v"(SL.q0), "=&v"(SL.q1),     \
                 "=&v"(SL.ga), "=&v"(SL.vv)                                  \
               : "v"(ka), "v"(qa), "v"(aa), "v"(va));                        \
  ka += 8192; qa += 8192; aa += 256; va += 8192;

__device__ __forceinline__ void do_step(const SlotR& X, float (&S)[8], float* ob,
                                        bool dostore, int tt) {
  const float eg = X.ga.x, bt = X.ga.y, qk = X.ga.z;
  float a0 = fmaf(X.k1.x, S[4], X.k0.x * S[0]);
  float a1 = fmaf(X.k1.y, S[5], X.k0.y * S[1]);
  float a2 = fmaf(X.k1.z, S[6], X.k0.z * S[2]);
  float a3 = fmaf(X.k1.w, S[7], X.k0.w * S[3]);
  float b0 = fmaf(X.q1.x, S[4], X.q0.x * S[0]);
  float b1 = fmaf(X.q1.y, S[5], X.q0.y * S[1]);
  float b2 = fmaf(X.q1.z, S[6], X.q0.z * S[2]);
  float b3 = fmaf(X.q1.w, S[7], X.q0.w * S[3]);
  float kS = red16d((a0 + a1) + (a2 + a3));
  float qS = red16d((b0 + b1) + (b2 + b3));
  float delta = fmaf(-(bt * eg), kS, bt * X.vv);   // bt*(v - eg*kS)
  S[0] = fmaf(X.k0.x, delta, eg * S[0]);
  S[1] = fmaf(X.k0.y, delta, eg * S[1]);
  S[2] = fmaf(X.k0.z, delta, eg * S[2]);
  S[3] = fmaf(X.k0.w, delta, eg * S[3]);
  S[4] = fmaf(X.k1.x, delta, eg * S[4]);
  S[5] = fmaf(X.k1.y, delta, eg * S[5]);
  S[6] = fmaf(X.k1.z, delta, eg * S[6]);
  S[7] = fmaf(X.k1.w, delta, eg * S[7]);
  if (dostore) ob[(size_t)tt * 2048] = fmaf(qk, delta, eg * qS);
}

// step i of a chunk: wait until this slot's 6 loads retired. Counts are on the
// 48 loads issued this iteration (loads retire in-order among loads, m135);
// only step 7's vmcnt(0) also drains stores (conservative, sound).
#define SCAN_STEP(SL, TT, CNT)                           \
  asm volatile("s_waitcnt vmcnt(" CNT ")" ::: "memory"); \
  __builtin_amdgcn_sched_barrier(0);                     \
  do_step(SL, S, ob, dostore, TT);

__global__ void __launch_bounds__(64, 1) scan_kernel(const float* __restrict__ q,
                                                     const float* __restrict__ k,
                                                     const float* __restrict__ v,
                                                     const float4* __restrict__ g4,
                                                     float* __restrict__ o) {
  const int b = blockIdx.x;         // 512 = 16 heads * 32 slices
  const int xcd = b & 7, r = b >> 3;
  const int h = (xcd << 1) | (r >> 5);   // XCD swizzle: heads 2x,2x+1 per XCD
  const int slice = r & 31;
  const int vbase = slice << 2;
  const int lane = threadIdx.x;
  const int kl = lane & 15, vl = lane >> 4;
  unsigned long long ka = (unsigned long long)(k + h * 128 + kl * 8);
  unsigned long long qa = (unsigned long long)(q + h * 128 + kl * 8);
  unsigned long long va = (unsigned long long)(v + h * 128 + vbase + vl);
  unsigned long long aa = (unsigned long long)((const float*)g4 + h * 4);
  float* ob = o + h * 128 + vbase + vl;
  const bool dostore = (kl == 0);
  float S[8] = {0, 0, 0, 0, 0, 0, 0, 0};
  for (int c = 0; c < 128; c++) {
    const int t = c * 8;
    SlotR s0, s1, s2, s3, s4, s5, s6, s7;
    ISSUE(s0) ISSUE(s1) ISSUE(s2) ISSUE(s3)
    ISSUE(s4) ISSUE(s5) ISSUE(s6) ISSUE(s7)
    SCAN_STEP(s0, t + 0, "42"); SCAN_STEP(s1, t + 1, "36");
    SCAN_STEP(s2, t + 2, "30"); SCAN_STEP(s3, t + 3, "24");
    SCAN_STEP(s4, t + 4, "18"); SCAN_STEP(s5, t + 5, "12");
    SCAN_STEP(s6, t + 6, "6");  SCAN_STEP(s7, t + 7, "0");
  }
}

// ---------- o_gated = bf16(rmsnorm_head(o)*w * silu(gate)) ----------
__global__ void __launch_bounds__(256) gate_o_kernel(const float* __restrict__ o,
                                                     const float* __restrict__ gate,
                                                     const float* __restrict__ onw,
                                                     unsigned short* __restrict__ ogb) {
  const int t = blockIdx.x, tid = threadIdx.x;
  const int c = tid << 3;
  const float* orow = o + (size_t)t * 2048 + c;
  float ov[8]; *(float4*)&ov[0] = *(const float4*)orow; *(float4*)&ov[4] = *(const float4*)(orow + 4);
  float ss = 0.f;
#pragma unroll
  for (int j = 0; j < 8; j++) ss += ov[j] * ov[j];
  ss = red16(ss);
  const float rn = rsqrtf(ss * (1.f / 128.f) + 1e-6f);
  const int dv = (tid & 15) << 3;
  float wv[8]; *(float4*)&wv[0] = *(const float4*)(onw + dv); *(float4*)&wv[4] = *(const float4*)(onw + dv + 4);
  const float* grow = gate + (size_t)t * 2048 + c;
  float gv[8]; *(float4*)&gv[0] = *(const float4*)grow; *(float4*)&gv[4] = *(const float4*)(grow + 4);
  u16x8 r;
#pragma unroll
  for (int j = 0; j < 8; j++) r[j] = f2bf(ov[j] * rn * wv[j] * silu_f(gv[j]));
  *(u16x8*)(ogb + (size_t)t * 2048 + c) = r;
}

// ---------- out = a + b + c ----------
__global__ void final_add3_kernel(const float* __restrict__ a, const float* __restrict__ b,
                                  const float* __restrict__ c, float* __restrict__ out) {
  const int NU = 1024 * 512;
  for (int u = blockIdx.x * blockDim.x + threadIdx.x; u < NU; u += gridDim.x * blockDim.x) {
    float4 va = ((const float4*)a)[u];
    float4 vb = ((const float4*)b)[u];
    float4 vc = ((const float4*)c)[u];
    va.x += vb.x + vc.x; va.y += vb.y + vc.y; va.z += vb.z + vc.z; va.w += vb.w + vc.w;
    ((float4*)out)[u] = va;
  }
}

// ---------- ws layout (bytes) ----------
constexpr size_t SZ_WQKVT   = (size_t)6144 * 2048 * 2;
constexpr size_t SZ_WSMALLT = (size_t)272 * 2048 * 2;
constexpr size_t SZ_WGBT    = (size_t)2048 * 128 * 2;
constexpr size_t SZ_WOT     = (size_t)2048 * 2048 * 2;
constexpr size_t SZ_WMLP1T  = (size_t)16384 * 2048 * 2;
constexpr size_t SZ_WDOWNT  = (size_t)2048 * 8192 * 2;
constexpr size_t OFF_WQKVT   = 0;
constexpr size_t OFF_WSMALLT = OFF_WQKVT + SZ_WQKVT;
constexpr size_t OFF_WGBT    = OFF_WSMALLT + SZ_WSMALLT;
constexpr size_t OFF_WOT     = OFF_WGBT + SZ_WGBT;
constexpr size_t OFF_WMLP1T  = OFF_WOT + SZ_WOT;
constexpr size_t OFF_WDOWNT  = OFF_WMLP1T + SZ_WMLP1T;
constexpr size_t A0          = OFF_WDOWNT + SZ_WDOWNT;
constexpr size_t OFF_HB    = A0;
constexpr size_t OFF_PROJ  = OFF_HB + (size_t)1024 * 2048 * 2;
constexpr size_t OFF_SMALL = OFF_PROJ + (size_t)1024 * 6144 * 4;
constexpr size_t OFF_Q     = OFF_SMALL + (size_t)1024 * 272 * 4;
constexpr size_t OFF_K     = OFF_Q + (size_t)1024 * 2048 * 4;
constexpr size_t OFF_V     = OFF_K + (size_t)1024 * 2048 * 4;
constexpr size_t OFF_G     = OFF_V + (size_t)1024 * 2048 * 4;
constexpr size_t OFF_BETA  = OFF_G + (size_t)1024 * 16 * 4;
constexpr size_t OFF_GAB   = OFF_BETA + (size_t)1024 * 16 * 4;
constexpr size_t OFF_GATE  = OFF_GAB + (size_t)1024 * 128 * 2;
constexpr size_t OFF_O     = OFF_GATE + (size_t)1024 * 2048 * 4;
constexpr size_t OFF_OGB   = OFF_O + (size_t)1024 * 2048 * 4;
constexpr size_t OFF_OPROJ = OFF_OGB + (size_t)1024 * 2048 * 2;
constexpr size_t OFF_X1    = OFF_OPROJ + (size_t)1024 * 2048 * 4;
constexpr size_t OFF_H2B   = OFF_X1 + (size_t)1024 * 2048 * 4;
constexpr size_t OFF_MID    = A0 + (size_t)1024 * 16384 * 4;
constexpr size_t OFF_MLPOUT = OFF_H2B + (size_t)1024 * 2048 * 2;
constexpr size_t OFF_QKB    = OFF_MLPOUT + (size_t)1024 * 2048 * 4;     // [1024][16] f32
constexpr size_t OFF_G4     = OFF_QKB + (size_t)1024 * 16 * 4;          // [1040][16] float4
constexpr size_t OFF_MLPOUT2= OFF_G4 + (size_t)1040 * 16 * 16;
constexpr size_t WS_NEED    = OFF_MLPOUT2 + (size_t)1024 * 2048 * 4;
constexpr size_t OFF_OPROJ2 = OFF_O;   // liveness alias

extern "C" void kernel_launch(void* const* d_in, const int* in_sizes, int n_in,
                              void* d_out, int out_size, void* d_ws, size_t ws_size,
                              hipStream_t stream) {
  (void)in_sizes; (void)n_in; (void)out_size;
  const float* x     = (const float*)d_in[0];
  const float* wq    = (const float*)d_in[1];
  const float* wk    = (const float*)d_in[2];
  const float* wv    = (const float*)d_in[3];
  const float* cq    = (const float*)d_in[4];
  const float* ck    = (const float*)d_in[5];
  const float* cv    = (const float*)d_in[6];
  const float* wfa   = (const float*)d_in[7];
  const float* wfb   = (const float*)d_in[8];
  const float* wb    = (const float*)d_in[9];
  const float* wga   = (const float*)d_in[10];
  const float* wgb   = (const float*)d_in[11];
  const float* a_log = (const float*)d_in[12];
  const float* dtb   = (const float*)d_in[13];
  const float* onw   = (const float*)d_in[14];
  const float* wo    = (const float*)d_in[15];
  const float* ln1   = (const float*)d_in[16];
  const float* ln2   = (const float*)d_in[17];
  const float* wgate = (const float*)d_in[18];
  const float* wup   = (const float*)d_in[19];
  const float* wdown = (const float*)d_in[20];
  float* out = (float*)d_out;
  char* ws = (char*)d_ws;
  if (ws_size < WS_NEED) return;

  unsigned short* wqkvT   = (unsigned short*)(ws + OFF_WQKVT);
  unsigned short* wsmallT = (unsigned short*)(ws + OFF_WSMALLT);
  unsigned short* wgbT    = (unsigned short*)(ws + OFF_WGBT);
  unsigned short* woT     = (unsigned short*)(ws + OFF_WOT);
  unsigned short* wmlp1T  = (unsigned short*)(ws + OFF_WMLP1T);
  unsigned short* wdownT  = (unsigned short*)(ws + OFF_WDOWNT);
  unsigned short* hb      = (unsigned short*)(ws + OFF_HB);
  float* projf  = (float*)(ws + OFF_PROJ);
  float* smallf = (float*)(ws + OFF_SMALL);
  float* qf     = (float*)(ws + OFF_Q);
  float* kf     = (float*)(ws + OFF_K);
  float* vf     = (float*)(ws + OFF_V);
  unsigned short* gab = (unsigned short*)(ws + OFF_GAB);
  float* gatef  = (float*)(ws + OFF_GATE);
  float* of     = (float*)(ws + OFF_O);
  unsigned short* ogb = (unsigned short*)(ws + OFF_OGB);
  float* oprojf = (float*)(ws + OFF_OPROJ);
  float* oproj2f= (float*)(ws + OFF_OPROJ2);
  float* x1f    = (float*)(ws + OFF_X1);
  unsigned short* h2b = (unsigned short*)(ws + OFF_H2B);
  unsigned short* midb = (unsigned short*)(ws + OFF_MID);
  float* mlpoutf = (float*)(ws + OFF_MLPOUT);
  float* mlpout2f = (float*)(ws + OFF_MLPOUT2);
  float* qkbuf  = (float*)(ws + OFF_QKB);
  float4* g4    = (float4*)(ws + OFF_G4);

  trans_kernel<<<dim3(64, 64), 256, 0, stream>>>(wq, wqkvT, 2048, 2048);
  trans_kernel<<<dim3(64, 64), 256, 0, stream>>>(wk, wqkvT + (size_t)2048 * 2048, 2048, 2048);
  trans_kernel<<<dim3(64, 64), 256, 0, stream>>>(wv, wqkvT + (size_t)4096 * 2048, 2048, 2048);
  trans_kernel<<<dim3(4, 64), 256, 0, stream>>>(wfa, wsmallT, 2048, 128);
  trans_kernel<<<dim3(1, 64), 256, 0, stream>>>(wb, wsmallT + (size_t)128 * 2048, 2048, 16);
  trans_kernel<<<dim3(4, 64), 256, 0, stream>>>(wga, wsmallT + (size_t)144 * 2048, 2048, 128);
  trans_kernel<<<dim3(64, 4), 256, 0, stream>>>(wgb, wgbT, 128, 2048);
  trans_kernel<<<dim3(64, 64), 256, 0, stream>>>(wo, woT, 2048, 2048);
  trans_kernel<<<dim3(256, 64), 256, 0, stream>>>(wgate, wmlp1T, 2048, 8192);
  trans_kernel<<<dim3(256, 64), 256, 0, stream>>>(wup, wmlp1T + (size_t)8192 * 2048, 2048, 8192);
  trans_kernel<<<dim3(64, 256), 256, 0, stream>>>(wdown, wdownT, 8192, 2048);

  rmsnorm_bf16_kernel<<<1024, 256, 0, stream>>>(x, ln1, hb);
  gemm_bt_kernel<<<dim3(8, 48), 256, 0, stream>>>(hb, wqkvT, projf, 1024, 6144, 2048, 2048, 2048);
  gemm_bt_kernel<<<dim3(8, 3), 256, 0, stream>>>(hb, wsmallT, smallf, 1024, 272, 2048, 2048, 2048);
  conv_kernel<<<1024, 256, 0, stream>>>(projf, cq, ck, cv, qf, kf, vf, qkbuf);
  gates_kernel<<<1024, 64, 0, stream>>>(smallf, wfb, a_log, dtb, qkbuf, g4, gab);
  gemm_bt_kernel<<<dim3(8, 16), 256, 0, stream>>>(gab, wgbT, gatef, 1024, 2048, 128, 128, 128);
  scan_kernel<<<512, 64, 0, stream>>>(qf, kf, vf, g4, of);
  gate_o_kernel<<<1024, 256, 0, stream>>>(of, gatef, onw, ogb);
  gemm_bt_kernel<<<dim3(8, 16), 256, 0, stream>>>(ogb, woT, oprojf, 1024, 2048, 1024, 2048, 2048);
  gemm_bt_kernel<<<dim3(8, 16), 256, 0, stream>>>(ogb + 1024, woT + 1024, oproj2f, 1024, 2048, 1024, 2048, 2048);
  add3_rmsnorm_kernel<<<1024, 256, 0, stream>>>(x, oprojf, oproj2f, ln2, x1f, h2b);
  gemm_dual_swiglu_kernel<<<dim3(8, 64), 256, 0, stream>>>(h2b, wmlp1T, midb);
  gemm_bt_kernel<<<dim3(8, 16), 256, 0, stream>>>(midb, wdownT, mlpoutf, 1024, 2048, 4096, 8192, 8192);
  gemm_bt_kernel<<<dim3(8, 16), 256, 0, stream>>>(midb + 4096, wdownT + 4096, mlpout2f, 1024, 2048, 4096, 8192, 8192);
  final_add3_kernel<<<2048, 256, 0, stream>>>(x1f, mlpoutf, mlpout2f, out);
}

// Round 10
// 783.620 us; speedup vs baseline: 1.2250x; 1.1515x over previous
//
#include <hip/hip_runtime.h>
#include <hip/hip_bf16.h>

typedef __attribute__((ext_vector_type(8))) short short8;
typedef __attribute__((ext_vector_type(4))) float f32x4;
typedef __attribute__((ext_vector_type(8))) unsigned short u16x8;
typedef __attribute__((ext_vector_type(4))) unsigned short u16x4;

// ---------- helpers ----------
__device__ __forceinline__ unsigned short f2bf(float f) {
  unsigned u = __float_as_uint(f);
  u += 0x7fffu + ((u >> 16) & 1u);          // round-to-nearest-even
  return (unsigned short)(u >> 16);
}
__device__ __forceinline__ float silu_f(float x) { return x / (1.f + __expf(-x)); }
__device__ __forceinline__ float red16(float v) {
  v += __shfl_xor(v, 1); v += __shfl_xor(v, 2);
  v += __shfl_xor(v, 4); v += __shfl_xor(v, 8);
  return v;
}
template <int CTRL>
__device__ __forceinline__ float dpp_mv(float v) {
  return __int_as_float(__builtin_amdgcn_update_dpp(0, __float_as_int(v), CTRL, 0xF, 0xF, true));
}
__device__ __forceinline__ float red16d(float v) {
  v += dpp_mv<0xB1>(v);   // quad_perm [1,0,3,2]
  v += dpp_mv<0x4E>(v);   // quad_perm [2,3,0,1]
  v += dpp_mv<0x141>(v);  // row_half_mirror
  v += dpp_mv<0x140>(v);  // row_mirror
  return v;
}
__device__ __forceinline__ void gload16(const void* g, void* l) {
  __builtin_amdgcn_global_load_lds((const __attribute__((address_space(1))) void*)g,
                                   (__attribute__((address_space(3))) void*)l, 16, 0, 0);
}

// ---------- transpose fp32 [R][C] -> bf16 [C][R], 64x64 tile ----------
// read: float4 per thread x4 (256B/16-lane row); store transposed into LDS
// (stride 65 -> <=2-way bank aliasing, free per m136); write u16x4 -> 128B
// contiguous per 16 lanes (vs 64B in the old 32x32 version).
__global__ void __launch_bounds__(256) trans64_kernel(const float* __restrict__ src,
                                                      unsigned short* __restrict__ dst,
                                                      int R, int C) {
  __shared__ float tile[64][65];   // tile[col'][row']
  const int tid = threadIdx.x;
  const int c0 = blockIdx.x * 64, r0 = blockIdx.y * 64;
  const int l = tid & 15, g = tid >> 4;   // l: 4-col / 4-row group, g: 0..15
#pragma unroll
  for (int i = 0; i < 4; i++) {
    const int r = r0 + g + 16 * i;
    const int c = c0 + 4 * l;
    if (r < R) {
      if (c + 3 < C) {
        float4 v = *(const float4*)(src + (size_t)r * C + c);
        tile[4 * l + 0][g + 16 * i] = v.x;
        tile[4 * l + 1][g + 16 * i] = v.y;
        tile[4 * l + 2][g + 16 * i] = v.z;
        tile[4 * l + 3][g + 16 * i] = v.w;
      } else {
#pragma unroll
        for (int j = 0; j < 4; j++)
          if (c + j < C) tile[4 * l + j][g + 16 * i] = src[(size_t)r * C + c + j];
      }
    }
  }
  __syncthreads();
#pragma unroll
  for (int i = 0; i < 4; i++) {
    const int cc = c0 + g + 16 * i;
    const int rc = r0 + 4 * l;
    if (cc < C) {
      if (rc + 3 < R) {
        u16x4 o;
        o[0] = f2bf(tile[g + 16 * i][4 * l + 0]);
        o[1] = f2bf(tile[g + 16 * i][4 * l + 1]);
        o[2] = f2bf(tile[g + 16 * i][4 * l + 2]);
        o[3] = f2bf(tile[g + 16 * i][4 * l + 3]);
        *(u16x4*)(dst + (size_t)cc * R + rc) = o;
      } else {
#pragma unroll
        for (int j = 0; j < 4; j++)
          if (rc + j < R) dst[(size_t)cc * R + rc + j] = f2bf(tile[g + 16 * i][4 * l + j]);
      }
    }
  }
}

// ---------- rmsnorm (D=2048) -> bf16 ----------
__global__ void __launch_bounds__(256) rmsnorm_bf16_kernel(const float* __restrict__ x,
                                                           const float* __restrict__ w,
                                                           unsigned short* __restrict__ outb) {
  const int t = blockIdx.x, tid = threadIdx.x;
  const float* xr = x + (size_t)t * 2048 + tid * 8;
  float4 v0 = *(const float4*)xr, v1 = *(const float4*)(xr + 4);
  float ss = v0.x*v0.x + v0.y*v0.y + v0.z*v0.z + v0.w*v0.w
           + v1.x*v1.x + v1.y*v1.y + v1.z*v1.z + v1.w*v1.w;
#pragma unroll
  for (int m = 1; m < 64; m <<= 1) ss += __shfl_xor(ss, m);
  __shared__ float sb[4];
  if ((tid & 63) == 0) sb[tid >> 6] = ss;
  __syncthreads();
  float rn = rsqrtf((sb[0] + sb[1] + sb[2] + sb[3]) * (1.f / 2048.f) + 1e-6f);
  const float* wr = w + tid * 8;
  float4 w0 = *(const float4*)wr, w1 = *(const float4*)(wr + 4);
  u16x8 r;
  r[0]=f2bf(v0.x*rn*w0.x); r[1]=f2bf(v0.y*rn*w0.y); r[2]=f2bf(v0.z*rn*w0.z); r[3]=f2bf(v0.w*rn*w0.w);
  r[4]=f2bf(v1.x*rn*w1.x); r[5]=f2bf(v1.y*rn*w1.y); r[6]=f2bf(v1.z*rn*w1.z); r[7]=f2bf(v1.w*rn*w1.w);
  *(u16x8*)(outb + (size_t)t * 2048 + tid * 8) = r;
}

// ---------- x1 = x + y1 + y2 ; h2b = bf16(rmsnorm(x1)*w) ----------
__global__ void __launch_bounds__(256) add3_rmsnorm_kernel(const float* __restrict__ x,
                                                           const float* __restrict__ y1,
                                                           const float* __restrict__ y2,
                                                           const float* __restrict__ w,
                                                           float* __restrict__ x1,
                                                           unsigned short* __restrict__ h2b) {
  const int t = blockIdx.x, tid = threadIdx.x;
  const int c = tid * 8;
  const float* xr = x + (size_t)t * 2048 + c;
  const float* yr = y1 + (size_t)t * 2048 + c;
  const float* zr = y2 + (size_t)t * 2048 + c;
  float s[8]; float ss = 0.f;
  float4 a0 = *(const float4*)xr, a1 = *(const float4*)(xr + 4);
  float4 b0 = *(const float4*)yr, b1 = *(const float4*)(yr + 4);
  float4 c0 = *(const float4*)zr, c1 = *(const float4*)(zr + 4);
  s[0]=a0.x+b0.x+c0.x; s[1]=a0.y+b0.y+c0.y; s[2]=a0.z+b0.z+c0.z; s[3]=a0.w+b0.w+c0.w;
  s[4]=a1.x+b1.x+c1.x; s[5]=a1.y+b1.y+c1.y; s[6]=a1.z+b1.z+c1.z; s[7]=a1.w+b1.w+c1.w;
#pragma unroll
  for (int j = 0; j < 8; j++) ss += s[j] * s[j];
#pragma unroll
  for (int m = 1; m < 64; m <<= 1) ss += __shfl_xor(ss, m);
  __shared__ float sb[4];
  if ((tid & 63) == 0) sb[tid >> 6] = ss;
  __syncthreads();
  float rn = rsqrtf((sb[0] + sb[1] + sb[2] + sb[3]) * (1.f / 2048.f) + 1e-6f);
  float* xo = x1 + (size_t)t * 2048 + c;
  *(float4*)xo = *(float4*)&s[0];
  *(float4*)(xo + 4) = *(float4*)&s[4];
  const float* wr = w + c;
  float4 w0 = *(const float4*)wr, w1 = *(const float4*)(wr + 4);
  float wv[8] = {w0.x,w0.y,w0.z,w0.w,w1.x,w1.y,w1.z,w1.w};
  u16x8 r;
#pragma unroll
  for (int j = 0; j < 8; j++) r[j] = f2bf(s[j] * rn * wv[j]);
  *(u16x8*)(h2b + (size_t)t * 2048 + c) = r;
}

// ---------- bf16 GEMM: C[M,N] = A[M,K] * Bt[N,K]^T  (m97-style, strided) ----------
__global__ void __launch_bounds__(256) gemm_bt_kernel(const unsigned short* __restrict__ A,
                                                      const unsigned short* __restrict__ Bt,
                                                      float* __restrict__ C,
                                                      int M, int N, int K, int lda, int ldb) {
  __shared__ unsigned short As[128][32];
  __shared__ unsigned short Bs[128][32];
  const int tid = threadIdx.x;
  const int m0 = blockIdx.x << 7, n0 = blockIdx.y << 7;
  const int wave = tid >> 6, lane = tid & 63;
  const int wm = (wave >> 1) << 6, wn = (wave & 1) << 6;
  const int lrow = lane >> 2, lcol = lane & 3;
  const int ar0 = wave * 16 + lrow;
  const int ar1 = ar0 + 64;
  int br0 = n0 + ar0; br0 = br0 < N ? br0 : N - 1;
  int br1 = n0 + ar1; br1 = br1 < N ? br1 : N - 1;
  const unsigned short* Aptr0 = A + (size_t)(m0 + ar0) * lda + ((lcol ^ (ar0 & 3)) << 3);
  const unsigned short* Aptr1 = A + (size_t)(m0 + ar1) * lda + ((lcol ^ (ar1 & 3)) << 3);
  const unsigned short* Bptr0 = Bt + (size_t)br0 * ldb + ((lcol ^ (ar0 & 3)) << 3);
  const unsigned short* Bptr1 = Bt + (size_t)br1 * ldb + ((lcol ^ (ar1 & 3)) << 3);
  unsigned short* lA0 = &As[wave * 16][0];
  unsigned short* lA1 = &As[64 + wave * 16][0];
  unsigned short* lB0 = &Bs[wave * 16][0];
  unsigned short* lB1 = &Bs[64 + wave * 16][0];
  const int frow = lane & 15, fkb = lane >> 4;
  f32x4 acc[4][4];
#pragma unroll
  for (int i = 0; i < 4; i++)
#pragma unroll
    for (int j = 0; j < 4; j++) acc[i][j] = (f32x4){0.f, 0.f, 0.f, 0.f};

  for (int k0 = 0; k0 < K; k0 += 32) {
    gload16(Aptr0 + k0, lA0);
    gload16(Aptr1 + k0, lA1);
    gload16(Bptr0 + k0, lB0);
    gload16(Bptr1 + k0, lB1);
    __syncthreads();
    short8 af[4], bfr[4];
#pragma unroll
    for (int i = 0; i < 4; i++) {
      int ra = wm + i * 16 + frow;
      af[i] = *(const short8*)&As[ra][(fkb ^ (ra & 3)) << 3];
      int rb = wn + i * 16 + frow;
      bfr[i] = *(const short8*)&Bs[rb][(fkb ^ (rb & 3)) << 3];
    }
#pragma unroll
    for (int i = 0; i < 4; i++)
#pragma unroll
      for (int j = 0; j < 4; j++)
        acc[i][j] = __builtin_amdgcn_mfma_f32_16x16x32_bf16(af[i], bfr[j], acc[i][j], 0, 0, 0);
    __syncthreads();
  }
  const int crow = (lane >> 4) << 2, ccol = lane & 15;
#pragma unroll
  for (int i = 0; i < 4; i++) {
    const int gr = m0 + wm + i * 16 + crow;
#pragma unroll
    for (int j = 0; j < 4; j++) {
      const int gc = n0 + wn + j * 16 + ccol;
      if (gc < N) {
#pragma unroll
        for (int r = 0; r < 4; r++) C[(size_t)(gr + r) * N + gc] = acc[i][j][r];
      }
    }
  }
}

// ---------- split-K x2 GEMM in ONE launch: blockIdx.z picks K-half ----------
// (two sequential 128-block launches used only half the CUs each; merged,
// all 256 blocks run concurrently)
__global__ void __launch_bounds__(256) gemm_bt_splitk2_kernel(const unsigned short* __restrict__ Abase,
                                                              const unsigned short* __restrict__ Btbase,
                                                              float* __restrict__ C0,
                                                              float* __restrict__ C1,
                                                              int M, int N, int Khalf,
                                                              int lda, int ldb) {
  const unsigned short* A = Abase + (size_t)blockIdx.z * Khalf;
  const unsigned short* Bt = Btbase + (size_t)blockIdx.z * Khalf;
  float* C = blockIdx.z ? C1 : C0;
  __shared__ unsigned short As[128][32];
  __shared__ unsigned short Bs[128][32];
  const int tid = threadIdx.x;
  const int m0 = blockIdx.x << 7, n0 = blockIdx.y << 7;
  const int wave = tid >> 6, lane = tid & 63;
  const int wm = (wave >> 1) << 6, wn = (wave & 1) << 6;
  const int lrow = lane >> 2, lcol = lane & 3;
  const int ar0 = wave * 16 + lrow;
  const int ar1 = ar0 + 64;
  int br0 = n0 + ar0; br0 = br0 < N ? br0 : N - 1;
  int br1 = n0 + ar1; br1 = br1 < N ? br1 : N - 1;
  const unsigned short* Aptr0 = A + (size_t)(m0 + ar0) * lda + ((lcol ^ (ar0 & 3)) << 3);
  const unsigned short* Aptr1 = A + (size_t)(m0 + ar1) * lda + ((lcol ^ (ar1 & 3)) << 3);
  const unsigned short* Bptr0 = Bt + (size_t)br0 * ldb + ((lcol ^ (ar0 & 3)) << 3);
  const unsigned short* Bptr1 = Bt + (size_t)br1 * ldb + ((lcol ^ (ar1 & 3)) << 3);
  unsigned short* lA0 = &As[wave * 16][0];
  unsigned short* lA1 = &As[64 + wave * 16][0];
  unsigned short* lB0 = &Bs[wave * 16][0];
  unsigned short* lB1 = &Bs[64 + wave * 16][0];
  const int frow = lane & 15, fkb = lane >> 4;
  f32x4 acc[4][4];
#pragma unroll
  for (int i = 0; i < 4; i++)
#pragma unroll
    for (int j = 0; j < 4; j++) acc[i][j] = (f32x4){0.f, 0.f, 0.f, 0.f};

  for (int k0 = 0; k0 < Khalf; k0 += 32) {
    gload16(Aptr0 + k0, lA0);
    gload16(Aptr1 + k0, lA1);
    gload16(Bptr0 + k0, lB0);
    gload16(Bptr1 + k0, lB1);
    __syncthreads();
    short8 af[4], bfr[4];
#pragma unroll
    for (int i = 0; i < 4; i++) {
      int ra = wm + i * 16 + frow;
      af[i] = *(const short8*)&As[ra][(fkb ^ (ra & 3)) << 3];
      int rb = wn + i * 16 + frow;
      bfr[i] = *(const short8*)&Bs[rb][(fkb ^ (rb & 3)) << 3];
    }
#pragma unroll
    for (int i = 0; i < 4; i++)
#pragma unroll
      for (int j = 0; j < 4; j++)
        acc[i][j] = __builtin_amdgcn_mfma_f32_16x16x32_bf16(af[i], bfr[j], acc[i][j], 0, 0, 0);
    __syncthreads();
  }
  const int crow = (lane >> 4) << 2, ccol = lane & 15;
#pragma unroll
  for (int i = 0; i < 4; i++) {
    const int gr = m0 + wm + i * 16 + crow;
#pragma unroll
    for (int j = 0; j < 4; j++) {
      const int gc = n0 + wn + j * 16 + ccol;
      if (gc < N) {
#pragma unroll
        for (int r = 0; r < 4; r++) C[(size_t)(gr + r) * N + gc] = acc[i][j][r];
      }
    }
  }
}

// ---------- fused MLP1: mid = bf16(silu(A*B1t^T) * (A*B2t^T)), N=8192, K=2048 ----------
__global__ void __launch_bounds__(256) gemm_dual_swiglu_kernel(const unsigned short* __restrict__ A,
                                                               const unsigned short* __restrict__ Bt,
                                                               unsigned short* __restrict__ mid) {
  __shared__ unsigned short As[128][32];
  __shared__ unsigned short B1s[128][32];
  __shared__ unsigned short B2s[128][32];
  const int tid = threadIdx.x;
  const int m0 = blockIdx.x << 7, n0 = blockIdx.y << 7;
  const int wave = tid >> 6, lane = tid & 63;
  const int wm = (wave >> 1) << 6, wn = (wave & 1) << 6;
  const int lrow = lane >> 2, lcol = lane & 3;
  const int ar0 = wave * 16 + lrow;
  const int ar1 = ar0 + 64;
  const unsigned short* Aptr0 = A + (size_t)(m0 + ar0) * 2048 + ((lcol ^ (ar0 & 3)) << 3);
  const unsigned short* Aptr1 = A + (size_t)(m0 + ar1) * 2048 + ((lcol ^ (ar1 & 3)) << 3);
  const unsigned short* B1p0 = Bt + (size_t)(n0 + ar0) * 2048 + ((lcol ^ (ar0 & 3)) << 3);
  const unsigned short* B1p1 = Bt + (size_t)(n0 + ar1) * 2048 + ((lcol ^ (ar1 & 3)) << 3);
  const unsigned short* B2p0 = B1p0 + (size_t)8192 * 2048;
  const unsigned short* B2p1 = B1p1 + (size_t)8192 * 2048;
  unsigned short* lA0 = &As[wave * 16][0];
  unsigned short* lA1 = &As[64 + wave * 16][0];
  unsigned short* lB10 = &B1s[wave * 16][0];
  unsigned short* lB11 = &B1s[64 + wave * 16][0];
  unsigned short* lB20 = &B2s[wave * 16][0];
  unsigned short* lB21 = &B2s[64 + wave * 16][0];
  const int frow = lane & 15, fkb = lane >> 4;
  f32x4 acc1[4][4], acc2[4][4];
#pragma unroll
  for (int i = 0; i < 4; i++)
#pragma unroll
    for (int j = 0; j < 4; j++) {
      acc1[i][j] = (f32x4){0.f, 0.f, 0.f, 0.f};
      acc2[i][j] = (f32x4){0.f, 0.f, 0.f, 0.f};
    }
  for (int k0 = 0; k0 < 2048; k0 += 32) {
    gload16(Aptr0 + k0, lA0);
    gload16(Aptr1 + k0, lA1);
    gload16(B1p0 + k0, lB10);
    gload16(B1p1 + k0, lB11);
    gload16(B2p0 + k0, lB20);
    gload16(B2p1 + k0, lB21);
    __syncthreads();
    short8 af[4], b1f[4], b2f[4];
#pragma unroll
    for (int i = 0; i < 4; i++) {
      int ra = wm + i * 16 + frow;
      af[i] = *(const short8*)&As[ra][(fkb ^ (ra & 3)) << 3];
      int rb = wn + i * 16 + frow;
      b1f[i] = *(const short8*)&B1s[rb][(fkb ^ (rb & 3)) << 3];
      b2f[i] = *(const short8*)&B2s[rb][(fkb ^ (rb & 3)) << 3];
    }
#pragma unroll
    for (int i = 0; i < 4; i++)
#pragma unroll
      for (int j = 0; j < 4; j++) {
        acc1[i][j] = __builtin_amdgcn_mfma_f32_16x16x32_bf16(af[i], b1f[j], acc1[i][j], 0, 0, 0);
        acc2[i][j] = __builtin_amdgcn_mfma_f32_16x16x32_bf16(af[i], b2f[j], acc2[i][j], 0, 0, 0);
      }
    __syncthreads();
  }
  const int crow = (lane >> 4) << 2, ccol = lane & 15;
#pragma unroll
  for (int i = 0; i < 4; i++) {
    const int gr = m0 + wm + i * 16 + crow;
#pragma unroll
    for (int j = 0; j < 4; j++) {
      const int gc = n0 + wn + j * 16 + ccol;
#pragma unroll
      for (int r = 0; r < 4; r++)
        mid[(size_t)(gr + r) * 8192 + gc] = f2bf(silu_f(acc1[i][j][r]) * acc2[i][j][r]);
    }
  }
}

// ---------- causal dwconv(K=4) + silu + per-head l2norm + qk dot ----------
__global__ void __launch_bounds__(256) conv_kernel(const float* __restrict__ proj,
                                                   const float* __restrict__ cq,
                                                   const float* __restrict__ ck,
                                                   const float* __restrict__ cv,
                                                   float* __restrict__ q, float* __restrict__ k,
                                                   float* __restrict__ v,
                                                   float* __restrict__ qkbuf) {
  const int t = blockIdx.x, tid = threadIdx.x;
  const int c = tid << 3;
  float aq[8] = {0,0,0,0,0,0,0,0}, ak[8] = {0,0,0,0,0,0,0,0}, av[8] = {0,0,0,0,0,0,0,0};
#pragma unroll
  for (int i = 0; i < 4; i++) {
    const int tt = t + i - 3;
    if (tt < 0) continue;
    const float* pr = proj + (size_t)tt * 6144;
    float pq[8], pk[8], pv[8], w0[8], w1[8], w2[8];
    *(float4*)&pq[0] = *(const float4*)(pr + c);        *(float4*)&pq[4] = *(const float4*)(pr + c + 4);
    *(float4*)&pk[0] = *(const float4*)(pr + 2048 + c); *(float4*)&pk[4] = *(const float4*)(pr + 2048 + c + 4);
    *(float4*)&pv[0] = *(const float4*)(pr + 4096 + c); *(float4*)&pv[4] = *(const float4*)(pr + 4096 + c + 4);
    *(float4*)&w0[0] = *(const float4*)(cq + i * 2048 + c); *(float4*)&w0[4] = *(const float4*)(cq + i * 2048 + c + 4);
    *(float4*)&w1[0] = *(const float4*)(ck + i * 2048 + c); *(float4*)&w1[4] = *(const float4*)(ck + i * 2048 + c + 4);
    *(float4*)&w2[0] = *(const float4*)(cv + i * 2048 + c); *(float4*)&w2[4] = *(const float4*)(cv + i * 2048 + c + 4);
#pragma unroll
    for (int j = 0; j < 8; j++) { aq[j] += w0[j]*pq[j]; ak[j] += w1[j]*pk[j]; av[j] += w2[j]*pv[j]; }
  }
  float sq[8], sk[8], sv[8]; float ssq = 0.f, ssk = 0.f;
#pragma unroll
  for (int j = 0; j < 8; j++) {
    sq[j] = silu_f(aq[j]); ssq += sq[j]*sq[j];
    sk[j] = silu_f(ak[j]); ssk += sk[j]*sk[j];
    sv[j] = silu_f(av[j]);
  }
  ssq = red16(ssq); ssk = red16(ssk);
  const float rq = rsqrtf(ssq + 1e-6f) * 0.08838834764831845f;  // * DK^-0.5
  const float rk = rsqrtf(ssk + 1e-6f);
  float oq[8], ok[8]; float qkl = 0.f;
#pragma unroll
  for (int j = 0; j < 8; j++) { oq[j] = sq[j]*rq; ok[j] = sk[j]*rk; qkl += oq[j]*ok[j]; }
  qkl = red16(qkl);
  if ((tid & 15) == 0) qkbuf[(size_t)t * 16 + (tid >> 4)] = qkl;
  float* qo = q + (size_t)t * 2048 + c;
  *(float4*)qo = *(float4*)&oq[0]; *(float4*)(qo + 4) = *(float4*)&oq[4];
  float* ko = k + (size_t)t * 2048 + c;
  *(float4*)ko = *(float4*)&ok[0]; *(float4*)(ko + 4) = *(float4*)&ok[4];
  float* vo = v + (size_t)t * 2048 + c;
  *(float4*)vo = *(float4*)&sv[0]; *(float4*)(vo + 4) = *(float4*)&sv[4];
}

// ---------- packed gates: g4[t][h] = (eg, beta, qk, 0); gab->bf16 ----------
__global__ void __launch_bounds__(64) gates_kernel(const float* __restrict__ small,
                                                   const float* __restrict__ wfb,
                                                   const float* __restrict__ a_log,
                                                   const float* __restrict__ dtb,
                                                   const float* __restrict__ qkbuf,
                                                   float4* __restrict__ g4,
                                                   unsigned short* __restrict__ gab) {
  const int t = blockIdx.x, tid = threadIdx.x;
  const float* srow = small + (size_t)t * 272;
  if (tid < 16) {
    float d = dtb[tid];
    for (int j = 0; j < 128; j++) d += srow[j] * wfb[j * 16 + tid];
    float sp = (d > 20.f) ? d : log1pf(expf(d));
    float eg = expf(-expf(a_log[tid]) * sp);
    float b = srow[128 + tid];
    float bt = 1.f / (1.f + expf(-b));
    g4[t * 16 + tid] = make_float4(eg, bt, qkbuf[t * 16 + tid], 0.f);
  }
  for (int j = tid; j < 128; j += 64) gab[(size_t)t * 128 + j] = f2bf(srow[144 + j]);
}

// ---------- gated delta-rule scan (C++ known-good: 8 named prefetch slots) ----------
struct Slot { float4 k0, k1, q0, q1; float eg, qk, btv, bteg; };

__device__ __forceinline__ void load_slot(Slot& X, const float* kb, const float* qb,
                                          const float* vb, const float4* g4b, int tt) {
  const float* kp = kb + (size_t)tt * 2048;
  const float* qp = qb + (size_t)tt * 2048;
  X.k0 = *(const float4*)kp; X.k1 = *(const float4*)(kp + 4);
  X.q0 = *(const float4*)qp; X.q1 = *(const float4*)(qp + 4);
  float4 g = g4b[(size_t)tt * 16];
  float v = vb[(size_t)tt * 2048];
  X.eg = g.x; X.qk = g.z;
  X.btv = g.y * v;            // off-chain precompute
  X.bteg = g.y * g.x;
}

__device__ __forceinline__ void step_slot(const Slot& X, float (&S)[8], float* ob,
                                          bool dostore, int tt) {
  float a0 = fmaf(X.k1.x, S[4], X.k0.x * S[0]);
  float a1 = fmaf(X.k1.y, S[5], X.k0.y * S[1]);
  float a2 = fmaf(X.k1.z, S[6], X.k0.z * S[2]);
  float a3 = fmaf(X.k1.w, S[7], X.k0.w * S[3]);
  float b0 = fmaf(X.q1.x, S[4], X.q0.x * S[0]);
  float b1 = fmaf(X.q1.y, S[5], X.q0.y * S[1]);
  float b2 = fmaf(X.q1.z, S[6], X.q0.z * S[2]);
  float b3 = fmaf(X.q1.w, S[7], X.q0.w * S[3]);
  float kS = red16d((a0 + a1) + (a2 + a3));
  float qS = red16d((b0 + b1) + (b2 + b3));
  float delta = fmaf(-X.bteg, kS, X.btv);   // bt*(v - eg*kS)
  S[0] = fmaf(X.k0.x, delta, X.eg * S[0]);
  S[1] = fmaf(X.k0.y, delta, X.eg * S[1]);
  S[2] = fmaf(X.k0.z, delta, X.eg * S[2]);
  S[3] = fmaf(X.k0.w, delta, X.eg * S[3]);
  S[4] = fmaf(X.k1.x, delta, X.eg * S[4]);
  S[5] = fmaf(X.k1.y, delta, X.eg * S[5]);
  S[6] = fmaf(X.k1.z, delta, X.eg * S[6]);
  S[7] = fmaf(X.k1.w, delta, X.eg * S[7]);
  if (dostore) ob[(size_t)tt * 2048] = fmaf(X.qk, delta, X.eg * qS);
}

__global__ void __launch_bounds__(64, 1) scan_kernel(const float* __restrict__ q,
                                                     const float* __restrict__ k,
                                                     const float* __restrict__ v,
                                                     const float4* __restrict__ g4,
                                                     float* __restrict__ o) {
  // XCD swizzle: b&7 = XCD -> heads 2x,2x+1 stay on one XCD
  const int b = blockIdx.x;            // 512 = 16 heads * 32 slices
  const int xcd = b & 7, r = b >> 3;
  const int h = (xcd << 1) | (r >> 5);
  const int vbase = (r & 31) << 2;
  const int lane = threadIdx.x;
  const int kl = lane & 15, vl = lane >> 4;
  const int vcol = vbase + vl;
  const int koff = h * 128 + kl * 8;
  const int voff = h * 128 + vcol;
  const float* kb = k + koff;
  const float* qb = q + koff;
  const float* vb = v + voff;
  const float4* g4b = g4 + h;
  float* ob = o + voff;
  const bool dostore = (kl == 0);
  float S[8] = {0,0,0,0,0,0,0,0};
  Slot s0, s1, s2, s3, s4, s5, s6, s7;
  load_slot(s0, kb, qb, vb, g4b, 0);
  load_slot(s1, kb, qb, vb, g4b, 1);
  load_slot(s2, kb, qb, vb, g4b, 2);
  load_slot(s3, kb, qb, vb, g4b, 3);
  load_slot(s4, kb, qb, vb, g4b, 4);
  load_slot(s5, kb, qb, vb, g4b, 5);
  load_slot(s6, kb, qb, vb, g4b, 6);
  load_slot(s7, kb, qb, vb, g4b, 7);
  // NOTE: prefetch reads past t=1023 land in adjacent ws regions (in-bounds,
  // never consumed) -- no clamp on the critical path.
  for (int t = 0; t < 1024; t += 8) {
    step_slot(s0, S, ob, dostore, t + 0); load_slot(s0, kb, qb, vb, g4b, t + 8);
    step_slot(s1, S, ob, dostore, t + 1); load_slot(s1, kb, qb, vb, g4b, t + 9);
    step_slot(s2, S, ob, dostore, t + 2); load_slot(s2, kb, qb, vb, g4b, t + 10);
    step_slot(s3, S, ob, dostore, t + 3); load_slot(s3, kb, qb, vb, g4b, t + 11);
    step_slot(s4, S, ob, dostore, t + 4); load_slot(s4, kb, qb, vb, g4b, t + 12);
    step_slot(s5, S, ob, dostore, t + 5); load_slot(s5, kb, qb, vb, g4b, t + 13);
    step_slot(s6, S, ob, dostore, t + 6); load_slot(s6, kb, qb, vb, g4b, t + 14);
    step_slot(s7, S, ob, dostore, t + 7); load_slot(s7, kb, qb, vb, g4b, t + 15);
  }
}

// ---------- o_gated = bf16(rmsnorm_head(o)*w * silu(gate)) ----------
__global__ void __launch_bounds__(256) gate_o_kernel(const float* __restrict__ o,
                                                     const float* __restrict__ gate,
                                                     const float* __restrict__ onw,
                                                     unsigned short* __restrict__ ogb) {
  const int t = blockIdx.x, tid = threadIdx.x;
  const int c = tid << 3;
  const float* orow = o + (size_t)t * 2048 + c;
  float ov[8]; *(float4*)&ov[0] = *(const float4*)orow; *(float4*)&ov[4] = *(const float4*)(orow + 4);
  float ss = 0.f;
#pragma unroll
  for (int j = 0; j < 8; j++) ss += ov[j] * ov[j];
  ss = red16(ss);
  const float rn = rsqrtf(ss * (1.f / 128.f) + 1e-6f);
  const int dv = (tid & 15) << 3;
  float wv[8]; *(float4*)&wv[0] = *(const float4*)(onw + dv); *(float4*)&wv[4] = *(const float4*)(onw + dv + 4);
  const float* grow = gate + (size_t)t * 2048 + c;
  float gv[8]; *(float4*)&gv[0] = *(const float4*)grow; *(float4*)&gv[4] = *(const float4*)(grow + 4);
  u16x8 r;
#pragma unroll
  for (int j = 0; j < 8; j++) r[j] = f2bf(ov[j] * rn * wv[j] * silu_f(gv[j]));
  *(u16x8*)(ogb + (size_t)t * 2048 + c) = r;
}

// ---------- out = a + b + c ----------
__global__ void final_add3_kernel(const float* __restrict__ a, const float* __restrict__ b,
                                  const float* __restrict__ c, float* __restrict__ out) {
  const int NU = 1024 * 512;
  for (int u = blockIdx.x * blockDim.x + threadIdx.x; u < NU; u += gridDim.x * blockDim.x) {
    float4 va = ((const float4*)a)[u];
    float4 vb = ((const float4*)b)[u];
    float4 vc = ((const float4*)c)[u];
    va.x += vb.x + vc.x; va.y += vb.y + vc.y; va.z += vb.z + vc.z; va.w += vb.w + vc.w;
    ((float4*)out)[u] = va;
  }
}

// ---------- ws layout (bytes) ----------
constexpr size_t SZ_WQKVT   = (size_t)6144 * 2048 * 2;
constexpr size_t SZ_WSMALLT = (size_t)272 * 2048 * 2;
constexpr size_t SZ_WGBT    = (size_t)2048 * 128 * 2;
constexpr size_t SZ_WOT     = (size_t)2048 * 2048 * 2;
constexpr size_t SZ_WMLP1T  = (size_t)16384 * 2048 * 2;
constexpr size_t SZ_WDOWNT  = (size_t)2048 * 8192 * 2;
constexpr size_t OFF_WQKVT   = 0;
constexpr size_t OFF_WSMALLT = OFF_WQKVT + SZ_WQKVT;
constexpr size_t OFF_WGBT    = OFF_WSMALLT + SZ_WSMALLT;
constexpr size_t OFF_WOT     = OFF_WGBT + SZ_WGBT;
constexpr size_t OFF_WMLP1T  = OFF_WOT + SZ_WOT;
constexpr size_t OFF_WDOWNT  = OFF_WMLP1T + SZ_WMLP1T;
constexpr size_t A0          = OFF_WDOWNT + SZ_WDOWNT;
constexpr size_t OFF_HB    = A0;
constexpr size_t OFF_PROJ  = OFF_HB + (size_t)1024 * 2048 * 2;
constexpr size_t OFF_SMALL = OFF_PROJ + (size_t)1024 * 6144 * 4;
constexpr size_t OFF_Q     = OFF_SMALL + (size_t)1024 * 272 * 4;
constexpr size_t OFF_K     = OFF_Q + (size_t)1024 * 2048 * 4;
constexpr size_t OFF_V     = OFF_K + (size_t)1024 * 2048 * 4;
constexpr size_t OFF_G     = OFF_V + (size_t)1024 * 2048 * 4;   // scan over-read pad
constexpr size_t OFF_BETA  = OFF_G + (size_t)1024 * 16 * 4;
constexpr size_t OFF_GAB   = OFF_BETA + (size_t)1024 * 16 * 4;
constexpr size_t OFF_GATE  = OFF_GAB + (size_t)1024 * 128 * 2;
constexpr size_t OFF_O     = OFF_GATE + (size_t)1024 * 2048 * 4;
constexpr size_t OFF_OGB   = OFF_O + (size_t)1024 * 2048 * 4;
constexpr size_t OFF_OPROJ = OFF_OGB + (size_t)1024 * 2048 * 2;
constexpr size_t OFF_X1    = OFF_OPROJ + (size_t)1024 * 2048 * 4;
constexpr size_t OFF_H2B   = OFF_X1 + (size_t)1024 * 2048 * 4;
constexpr size_t OFF_MID    = A0 + (size_t)1024 * 16384 * 4;   // overlaps dead GATE/O/OGB/OPROJ only
constexpr size_t OFF_MLPOUT = OFF_H2B + (size_t)1024 * 2048 * 2;
constexpr size_t OFF_QKB    = OFF_MLPOUT + (size_t)1024 * 2048 * 4;     // [1024][16] f32
constexpr size_t OFF_G4     = OFF_QKB + (size_t)1024 * 16 * 4;          // [1040][16] float4 (tail pad)
constexpr size_t OFF_MLPOUT2= OFF_G4 + (size_t)1040 * 16 * 16;
constexpr size_t WS_NEED    = OFF_MLPOUT2 + (size_t)1024 * 2048 * 4;
constexpr size_t OFF_OPROJ2 = OFF_O;   // liveness alias

extern "C" void kernel_launch(void* const* d_in, const int* in_sizes, int n_in,
                              void* d_out, int out_size, void* d_ws, size_t ws_size,
                              hipStream_t stream) {
  (void)in_sizes; (void)n_in; (void)out_size;
  const float* x     = (const float*)d_in[0];
  const float* wq    = (const float*)d_in[1];
  const float* wk    = (const float*)d_in[2];
  const float* wv    = (const float*)d_in[3];
  const float* cq    = (const float*)d_in[4];
  const float* ck    = (const float*)d_in[5];
  const float* cv    = (const float*)d_in[6];
  const float* wfa   = (const float*)d_in[7];
  const float* wfb   = (const float*)d_in[8];
  const float* wb    = (const float*)d_in[9];
  const float* wga   = (const float*)d_in[10];
  const float* wgb   = (const float*)d_in[11];
  const float* a_log = (const float*)d_in[12];
  const float* dtb   = (const float*)d_in[13];
  const float* onw   = (const float*)d_in[14];
  const float* wo    = (const float*)d_in[15];
  const float* ln1   = (const float*)d_in[16];
  const float* ln2   = (const float*)d_in[17];
  const float* wgate = (const float*)d_in[18];
  const float* wup   = (const float*)d_in[19];
  const float* wdown = (const float*)d_in[20];
  float* out = (float*)d_out;
  char* ws = (char*)d_ws;
  if (ws_size < WS_NEED) return;

  unsigned short* wqkvT   = (unsigned short*)(ws + OFF_WQKVT);
  unsigned short* wsmallT = (unsigned short*)(ws + OFF_WSMALLT);
  unsigned short* wgbT    = (unsigned short*)(ws + OFF_WGBT);
  unsigned short* woT     = (unsigned short*)(ws + OFF_WOT);
  unsigned short* wmlp1T  = (unsigned short*)(ws + OFF_WMLP1T);
  unsigned short* wdownT  = (unsigned short*)(ws + OFF_WDOWNT);
  unsigned short* hb      = (unsigned short*)(ws + OFF_HB);
  float* projf  = (float*)(ws + OFF_PROJ);
  float* smallf = (float*)(ws + OFF_SMALL);
  float* qf     = (float*)(ws + OFF_Q);
  float* kf     = (float*)(ws + OFF_K);
  float* vf     = (float*)(ws + OFF_V);
  unsigned short* gab = (unsigned short*)(ws + OFF_GAB);
  float* gatef  = (float*)(ws + OFF_GATE);
  float* of     = (float*)(ws + OFF_O);
  unsigned short* ogb = (unsigned short*)(ws + OFF_OGB);
  float* oprojf = (float*)(ws + OFF_OPROJ);
  float* oproj2f= (float*)(ws + OFF_OPROJ2);
  float* x1f    = (float*)(ws + OFF_X1);
  unsigned short* h2b = (unsigned short*)(ws + OFF_H2B);
  unsigned short* midb = (unsigned short*)(ws + OFF_MID);
  float* mlpoutf = (float*)(ws + OFF_MLPOUT);
  float* mlpout2f = (float*)(ws + OFF_MLPOUT2);
  float* qkbuf  = (float*)(ws + OFF_QKB);
  float4* g4    = (float4*)(ws + OFF_G4);

  trans64_kernel<<<dim3(32, 32), 256, 0, stream>>>(wq, wqkvT, 2048, 2048);
  trans64_kernel<<<dim3(32, 32), 256, 0, stream>>>(wk, wqkvT + (size_t)2048 * 2048, 2048, 2048);
  trans64_kernel<<<dim3(32, 32), 256, 0, stream>>>(wv, wqkvT + (size_t)4096 * 2048, 2048, 2048);
  trans64_kernel<<<dim3(2, 32), 256, 0, stream>>>(wfa, wsmallT, 2048, 128);
  trans64_kernel<<<dim3(1, 32), 256, 0, stream>>>(wb, wsmallT + (size_t)128 * 2048, 2048, 16);
  trans64_kernel<<<dim3(2, 32), 256, 0, stream>>>(wga, wsmallT + (size_t)144 * 2048, 2048, 128);
  trans64_kernel<<<dim3(32, 2), 256, 0, stream>>>(wgb, wgbT, 128, 2048);
  trans64_kernel<<<dim3(32, 32), 256, 0, stream>>>(wo, woT, 2048, 2048);
  trans64_kernel<<<dim3(128, 32), 256, 0, stream>>>(wgate, wmlp1T, 2048, 8192);
  trans64_kernel<<<dim3(128, 32), 256, 0, stream>>>(wup, wmlp1T + (size_t)8192 * 2048, 2048, 8192);
  trans64_kernel<<<dim3(32, 128), 256, 0, stream>>>(wdown, wdownT, 8192, 2048);

  rmsnorm_bf16_kernel<<<1024, 256, 0, stream>>>(x, ln1, hb);
  gemm_bt_kernel<<<dim3(8, 48), 256, 0, stream>>>(hb, wqkvT, projf, 1024, 6144, 2048, 2048, 2048);
  gemm_bt_kernel<<<dim3(8, 3), 256, 0, stream>>>(hb, wsmallT, smallf, 1024, 272, 2048, 2048, 2048);
  conv_kernel<<<1024, 256, 0, stream>>>(projf, cq, ck, cv, qf, kf, vf, qkbuf);
  gates_kernel<<<1024, 64, 0, stream>>>(smallf, wfb, a_log, dtb, qkbuf, g4, gab);
  gemm_bt_kernel<<<dim3(8, 16), 256, 0, stream>>>(gab, wgbT, gatef, 1024, 2048, 128, 128, 128);
  scan_kernel<<<512, 64, 0, stream>>>(qf, kf, vf, g4, of);
  gate_o_kernel<<<1024, 256, 0, stream>>>(of, gatef, onw, ogb);
  // wo: split-K x2 in ONE launch (256 blocks concurrent)
  gemm_bt_splitk2_kernel<<<dim3(8, 16, 2), 256, 0, stream>>>(ogb, woT, oprojf, oproj2f,
                                                             1024, 2048, 1024, 2048, 2048);
  add3_rmsnorm_kernel<<<1024, 256, 0, stream>>>(x, oprojf, oproj2f, ln2, x1f, h2b);
  gemm_dual_swiglu_kernel<<<dim3(8, 64), 256, 0, stream>>>(h2b, wmlp1T, midb);
  // down-proj: split-K x2 in ONE launch (256 blocks concurrent)
  gemm_bt_splitk2_kernel<<<dim3(8, 16, 2), 256, 0, stream>>>(midb, wdownT, mlpoutf, mlpout2f,
                                                             1024, 2048, 4096, 8192, 8192);
  final_add3_kernel<<<2048, 256, 0, stream>>>(x1f, mlpoutf, mlpout2f, out);
}